// Round 1
// baseline (615.542 us; speedup 1.0000x reference)
//
#include <hip/hip_runtime.h>
#include <math.h>

#define B_ 8
#define L_ 1024
#define DM 256      // d_model == CIN
#define DI 512      // d_inner
#define HD 32       // headdim
#define NH 16       // nheads
#define DS 128      // d_state
#define CDIM 768    // conv dim
#define DPROJ 1296  // in_proj out dim
#define CH 256      // chunk
#define NC 4        // L/CHUNK
#define M_ (B_*L_)  // 8192 rows
#define EPSV 1e-5f

// ---- workspace layout (floats). total = 31,850,496 floats = 127.4 MB ----
#define OFF_ZX  0
#define SZ_ZX   (M_*DPROJ)
#define OFF_XC  (OFF_ZX+SZ_ZX)
#define SZ_XC   (M_*CDIM)
#define OFF_DT  (OFF_XC+SZ_XC)
#define SZ_DT   (M_*NH)
#define OFF_ACS (OFF_DT+SZ_DT)
#define SZ_ACS  (B_*NC*NH*CH)
#define OFF_S0  (OFF_ACS+SZ_ACS)
#define SZ_S0   (B_*NC*CH*CH)
#define OFF_ST  (OFF_S0+SZ_S0)
#define SZ_ST   (B_*NC*NH*HD*DS)
#define OFF_PV  (OFF_ST+SZ_ST)
#define SZ_PV   SZ_ST
#define OFF_Y   (OFF_PV+SZ_PV)
#define SZ_Y    (M_*DI)
#define OFF_YN  (OFF_Y+SZ_Y)
#define SZ_YN   (M_*DI)

// ---------- 1) in-proj GEMM: zx[m,n] = sum_k x[b,k,l] * W_in[n,k] ----------
__global__ __launch_bounds__(256) void k_gemm_in(const float* __restrict__ x,
                                                 const float* __restrict__ W,
                                                 float* __restrict__ zx) {
  __shared__ float As[16][65];   // [k][m]
  __shared__ float Bs[16][65];   // [k][n]
  const int tid = threadIdx.x;
  const int n0 = blockIdx.x * 64;
  const int m0 = blockIdx.y * 64;
  const int b  = m0 >> 10;
  const int l0 = m0 & 1023;
  const int tr = tid >> 4, tc = tid & 15;
  float acc[4][4] = {};
  for (int k0 = 0; k0 < DM; k0 += 16) {
    for (int i = tid; i < 1024; i += 256) {
      int kk = i >> 6, mm = i & 63;                       // coalesced along l
      As[kk][mm] = x[(size_t)b*DM*L_ + (size_t)(k0+kk)*L_ + l0 + mm];
    }
    for (int i = tid; i < 1024; i += 256) {
      int nn = i >> 4, kk = i & 15;                       // 16-float runs along k
      int n = n0 + nn;
      Bs[kk][nn] = (n < DPROJ) ? W[(size_t)n*DM + k0 + kk] : 0.f;
    }
    __syncthreads();
#pragma unroll
    for (int k = 0; k < 16; ++k) {
      float a[4], bb[4];
#pragma unroll
      for (int i = 0; i < 4; ++i) a[i] = As[k][tr*4+i];
#pragma unroll
      for (int j = 0; j < 4; ++j) bb[j] = Bs[k][tc*4+j];
#pragma unroll
      for (int i = 0; i < 4; ++i)
#pragma unroll
        for (int j = 0; j < 4; ++j) acc[i][j] += a[i]*bb[j];
    }
    __syncthreads();
  }
  for (int i = 0; i < 4; ++i) {
    int m = m0 + tr*4 + i;
    for (int j = 0; j < 4; ++j) {
      int n = n0 + tc*4 + j;
      if (n < DPROJ) zx[(size_t)m*DPROJ + n] = acc[i][j];
    }
  }
}

// ---------- 2) dt = softplus(zx[...,1280+h] + dt_bias[h]) ----------
__global__ void k_dt(const float* __restrict__ zx, const float* __restrict__ dt_bias,
                     float* __restrict__ dtb) {
  int idx = blockIdx.x*256 + threadIdx.x;
  if (idx >= M_*NH) return;
  int m = idx >> 4, h = idx & 15;
  float v = zx[(size_t)m*DPROJ + (DI+CDIM) + h] + dt_bias[h];
  dtb[idx] = (v > 20.f) ? v : log1pf(expf(v));
}

// ---------- 3) causal conv4 + SiLU over xBC ----------
__global__ void k_conv(const float* __restrict__ zx, const float* __restrict__ cw,
                       const float* __restrict__ cb, float* __restrict__ xc) {
  int j = blockIdx.x*256 + threadIdx.x;   // 0..767
  int m = blockIdx.y;                     // 0..8191
  if (j >= CDIM) return;
  int l = m & 1023;
  int mb = m - l;                         // b*1024
  float acc = cb[j];
#pragma unroll
  for (int k = 0; k < 4; ++k) {
    int ll = l - 3 + k;
    if (ll >= 0) acc += cw[j*4+k] * zx[(size_t)(mb+ll)*DPROJ + DI + j];
  }
  acc = acc / (1.f + expf(-acc));         // silu
  xc[(size_t)m*CDIM + j] = acc;
}

// ---------- 4) S0[bc,l,s] = sum_n Cm[l,n]*Bm[s,n] (full 256x256 per (b,c)) ----------
__global__ __launch_bounds__(256) void k_s0(const float* __restrict__ xc,
                                            float* __restrict__ S0) {
  __shared__ float As[16][65];  // [k][l] (Cm)
  __shared__ float Bs[16][65];  // [k][s] (Bm)
  const int tid = threadIdx.x;
  const int l0 = blockIdx.x * 64;
  const int s0 = blockIdx.y * 64;
  const int bc = blockIdx.z;
  const int base = bc * CH;
  const int tr = tid >> 4, tc = tid & 15;
  float acc[4][4] = {};
  for (int k0 = 0; k0 < DS; k0 += 16) {
    for (int i = tid; i < 1024; i += 256) {
      int mm = i >> 4, kk = i & 15;
      As[kk][mm] = xc[(size_t)(base+l0+mm)*CDIM + (DI+DS) + k0 + kk]; // Cm
      Bs[kk][mm] = xc[(size_t)(base+s0+mm)*CDIM + DI + k0 + kk];      // Bm
    }
    __syncthreads();
#pragma unroll
    for (int k = 0; k < 16; ++k) {
      float a[4], bb[4];
#pragma unroll
      for (int i = 0; i < 4; ++i) a[i] = As[k][tr*4+i];
#pragma unroll
      for (int j = 0; j < 4; ++j) bb[j] = Bs[k][tc*4+j];
#pragma unroll
      for (int i = 0; i < 4; ++i)
#pragma unroll
        for (int j = 0; j < 4; ++j) acc[i][j] += a[i]*bb[j];
    }
    __syncthreads();
  }
  for (int i = 0; i < 4; ++i)
    for (int j = 0; j < 4; ++j)
      S0[((size_t)bc*CH + l0+tr*4+i)*CH + s0+tc*4+j] = acc[i][j];
}

// ---------- 5) per (b,c,h): cumsum(dt*A) + chunk states ----------
__global__ __launch_bounds__(256) void k_states(const float* __restrict__ xc,
                                                const float* __restrict__ dtb,
                                                const float* __restrict__ A_log,
                                                float* __restrict__ acs_g,
                                                float* __restrict__ st) {
  __shared__ float Xs[CH][HD+1];
  __shared__ float acs[CH];
  __shared__ float wv[CH];
  const int t = threadIdx.x;
  const int bc = blockIdx.x, h = blockIdx.y;
  const int base = bc * CH;
  float dt_t = dtb[(size_t)(base+t)*NH + h];
  float An = -expf(A_log[h]);
  acs[t] = dt_t * An;
  for (int i = t; i < CH*HD; i += 256) {
    int l = i >> 5, p = i & 31;
    Xs[l][p] = xc[(size_t)(base+l)*CDIM + h*HD + p];   // raw xs
  }
  __syncthreads();
  for (int off = 1; off < CH; off <<= 1) {             // inclusive scan
    float v = (t >= off) ? acs[t-off] : 0.f;
    __syncthreads();
    acs[t] += v;
    __syncthreads();
  }
  float alast = acs[CH-1];
  acs_g[((size_t)bc*NH + h)*CH + t] = acs[t];
  wv[t] = expf(alast - acs[t]) * dt_t;                 // decay * dt
  __syncthreads();
  const int n = t & 127, ph = t >> 7;
  float acc[16];
#pragma unroll
  for (int i = 0; i < 16; ++i) acc[i] = 0.f;
  for (int l = 0; l < CH; ++l) {
    float bw = xc[(size_t)(base+l)*CDIM + DI + n] * wv[l];  // Bm * decay * dt
#pragma unroll
    for (int i = 0; i < 16; ++i) acc[i] += bw * Xs[l][ph*16+i];
  }
  size_t sb = ((size_t)bc*NH + h)*HD*DS;
  for (int i = 0; i < 16; ++i) st[sb + (size_t)(ph*16+i)*DS + n] = acc[i];
}

// ---------- 6) inter-chunk scan: prev[c] = P, P = st[c] + exp(T[c])*P ----------
__global__ void k_scan(const float* __restrict__ acs_g, const float* __restrict__ st,
                       float* __restrict__ pv) {
  const int b = blockIdx.x, h = blockIdx.y;
  const int t = threadIdx.x;
  float P[16];
#pragma unroll
  for (int i = 0; i < 16; ++i) P[i] = 0.f;
  for (int c = 0; c < NC; ++c) {
    size_t sb = ((size_t)(b*NC+c)*NH + h)*HD*DS;
    float T = acs_g[((size_t)(b*NC+c)*NH + h)*CH + (CH-1)];
    float ec = expf(T);
#pragma unroll
    for (int i = 0; i < 16; ++i) {
      size_t e = sb + (size_t)i*256 + t;
      pv[e] = P[i];
      P[i] = st[e] + ec * P[i];
    }
  }
}

// ---------- 7) Y = Y_diag + Y_off + D*xs ----------
__global__ __launch_bounds__(256) void k_y(const float* __restrict__ xc,
                                           const float* __restrict__ dtb,
                                           const float* __restrict__ acs_g,
                                           const float* __restrict__ S0,
                                           const float* __restrict__ pv,
                                           const float* __restrict__ Dp,
                                           float* __restrict__ Y) {
  __shared__ float Xs[CH][HD+1];
  __shared__ float prevS[HD][DS+1];
  __shared__ float acs[CH];
  __shared__ float dts[CH];
  const int t = threadIdx.x;
  const int bc = blockIdx.x, h = blockIdx.y;
  const int base = bc * CH;
  for (int i = t; i < CH*HD; i += 256) {
    int l = i >> 5, p = i & 31;
    Xs[l][p] = xc[(size_t)(base+l)*CDIM + h*HD + p];
  }
  size_t pb = ((size_t)bc*NH + h)*HD*DS;
  for (int i = t; i < HD*DS; i += 256) prevS[i>>7][i&127] = pv[pb + i];
  acs[t] = acs_g[((size_t)bc*NH + h)*CH + t];
  dts[t] = dtb[(size_t)(base+t)*NH + h];
  __syncthreads();
  const int l = t;
  float acc[HD];
#pragma unroll
  for (int p = 0; p < HD; ++p) acc[p] = 0.f;
  // Y_off = exp(acs[l]) * Cm[l,:] @ prev^T
  for (int n = 0; n < DS; ++n) {
    float cv = xc[(size_t)(base+l)*CDIM + (DI+DS) + n];
#pragma unroll
    for (int p = 0; p < HD; ++p) acc[p] += cv * prevS[p][n];
  }
  float eA = expf(acs[l]);
#pragma unroll
  for (int p = 0; p < HD; ++p) acc[p] *= eA;
  // Y_diag: masked scores, wave-capped loop
  const int wlim = ((t >> 6) + 1) * 64;
  const float* srow = S0 + (size_t)(bc*CH + l)*CH;
  for (int s = 0; s < wlim; ++s) {
    float d = (s <= l) ? (acs[l] - acs[s]) : -1e30f;
    float sc = srow[s] * expf(d) * dts[s];
#pragma unroll
    for (int p = 0; p < HD; ++p) acc[p] += sc * Xs[s][p];
  }
  float dph = Dp[h];
  size_t ob = (size_t)(base+l)*DI + h*HD;
#pragma unroll
  for (int p = 0; p < HD; ++p) Y[ob+p] = acc[p] + dph * Xs[l][p];
}

// ---------- 8) gate with silu(z) + RMSNorm ----------
__global__ __launch_bounds__(256) void k_rms(const float* __restrict__ zx,
                                             const float* __restrict__ Y,
                                             const float* __restrict__ rw,
                                             float* __restrict__ yn) {
  const int m = blockIdx.x, t = threadIdx.x;
  float z0 = zx[(size_t)m*DPROJ + t];
  float z1 = zx[(size_t)m*DPROJ + t + 256];
  float y0 = Y[(size_t)m*DI + t]       * z0 / (1.f + expf(-z0));
  float y1 = Y[(size_t)m*DI + t + 256] * z1 / (1.f + expf(-z1));
  float ss = y0*y0 + y1*y1;
#pragma unroll
  for (int off = 32; off > 0; off >>= 1) ss += __shfl_down(ss, off);
  __shared__ float red[4];
  __shared__ float sinv;
  if ((t & 63) == 0) red[t >> 6] = ss;
  __syncthreads();
  if (t == 0) sinv = rsqrtf((red[0]+red[1]+red[2]+red[3]) * (1.f/DI) + EPSV);
  __syncthreads();
  float inv = sinv;
  yn[(size_t)m*DI + t]       = y0 * inv * rw[t];
  yn[(size_t)m*DI + t + 256] = y1 * inv * rw[t+256];
}

// ---------- 9) out-proj GEMM, store transposed (B, DM, L) ----------
__global__ __launch_bounds__(256) void k_gemm_out(const float* __restrict__ yn,
                                                  const float* __restrict__ W,
                                                  float* __restrict__ outp) {
  __shared__ float As[16][65];   // [k][m]
  __shared__ float Bs[16][65];   // [k][n]
  const int tid = threadIdx.x;
  const int m0 = blockIdx.x * 64;
  const int n0 = blockIdx.y * 64;
  const int b  = m0 >> 10, l0 = m0 & 1023;
  const int tr = tid >> 4, tc = tid & 15;
  float acc[4][4] = {};
  for (int k0 = 0; k0 < DI; k0 += 16) {
    for (int i = tid; i < 1024; i += 256) {
      int mm = i >> 4, kk = i & 15;
      As[kk][mm] = yn[(size_t)(m0+mm)*DI + k0 + kk];
      Bs[kk][mm] = W[(size_t)(n0+mm)*DI + k0 + kk];
    }
    __syncthreads();
#pragma unroll
    for (int k = 0; k < 16; ++k) {
      float av[4], bv[4];
#pragma unroll
      for (int j = 0; j < 4; ++j) av[j] = As[k][tc*4+j];   // m-dir
#pragma unroll
      for (int i = 0; i < 4; ++i) bv[i] = Bs[k][tr*4+i];   // n-dir
#pragma unroll
      for (int i = 0; i < 4; ++i)
#pragma unroll
        for (int j = 0; j < 4; ++j) acc[i][j] += bv[i]*av[j];
    }
    __syncthreads();
  }
  for (int i = 0; i < 4; ++i) {
    int n = n0 + tr*4 + i;
    for (int j = 0; j < 4; ++j) {
      int l = l0 + tc*4 + j;
      outp[(size_t)b*DM*L_ + (size_t)n*L_ + l] = acc[i][j];  // coalesced along l
    }
  }
}

// ---------- 10) GroupNorm + Mish, in-place on d_out ----------
__global__ __launch_bounds__(256) void k_gn(const float* __restrict__ gw,
                                            const float* __restrict__ gb,
                                            float* __restrict__ o) {
  const int b = blockIdx.x, g = blockIdx.y;
  const int t = threadIdx.x;
  size_t base = (size_t)b*DM*L_ + (size_t)g*32*L_;
  float s = 0.f, ss = 0.f;
  for (int i = t; i < 32*L_; i += 256) {
    float v = o[base+i];
    s += v; ss += v*v;
  }
#pragma unroll
  for (int off = 32; off > 0; off >>= 1) { s += __shfl_down(s, off); ss += __shfl_down(ss, off); }
  __shared__ float rs[4], rss[4];
  __shared__ float smean, sinv;
  if ((t & 63) == 0) { rs[t>>6] = s; rss[t>>6] = ss; }
  __syncthreads();
  if (t == 0) {
    float S = rs[0]+rs[1]+rs[2]+rs[3];
    float SS = rss[0]+rss[1]+rss[2]+rss[3];
    float mean = S * (1.f/(32.f*L_));
    float var  = SS * (1.f/(32.f*L_)) - mean*mean;
    smean = mean; sinv = rsqrtf(var + EPSV);
  }
  __syncthreads();
  float mean = smean, inv = sinv;
  for (int i = t; i < 32*L_; i += 256) {
    int ch = g*32 + (i >> 10);
    float v = (o[base+i] - mean) * inv * gw[ch] + gb[ch];
    float sp = (v > 20.f) ? v : log1pf(expf(v));
    o[base+i] = v * tanhf(sp);                       // mish
  }
}

extern "C" void kernel_launch(void* const* d_in, const int* in_sizes, int n_in,
                              void* d_out, int out_size, void* d_ws, size_t ws_size,
                              hipStream_t stream) {
  const float* x       = (const float*)d_in[0];
  const float* W_in    = (const float*)d_in[1];
  const float* conv_w  = (const float*)d_in[2];
  const float* conv_b  = (const float*)d_in[3];
  const float* dt_bias = (const float*)d_in[4];
  const float* A_log   = (const float*)d_in[5];
  const float* Dp      = (const float*)d_in[6];
  const float* rms_w   = (const float*)d_in[7];
  const float* W_out   = (const float*)d_in[8];
  const float* gn_w    = (const float*)d_in[9];
  const float* gn_b    = (const float*)d_in[10];
  float* out = (float*)d_out;
  float* ws  = (float*)d_ws;

  float* zx    = ws + OFF_ZX;
  float* xc    = ws + OFF_XC;
  float* dtb   = ws + OFF_DT;
  float* acs   = ws + OFF_ACS;
  float* S0    = ws + OFF_S0;
  float* st    = ws + OFF_ST;
  float* pv    = ws + OFF_PV;
  float* Ybuf  = ws + OFF_Y;
  float* ynorm = ws + OFF_YN;

  k_gemm_in <<<dim3(21, 128), 256, 0, stream>>>(x, W_in, zx);
  k_dt      <<<dim3((M_*NH)/256), 256, 0, stream>>>(zx, dt_bias, dtb);
  k_conv    <<<dim3(3, M_), 256, 0, stream>>>(zx, conv_w, conv_b, xc);
  k_s0      <<<dim3(4, 4, B_*NC), 256, 0, stream>>>(xc, S0);
  k_states  <<<dim3(B_*NC, NH), 256, 0, stream>>>(xc, dtb, A_log, acs, st);
  k_scan    <<<dim3(B_, NH), 256, 0, stream>>>(acs, st, pv);
  k_y       <<<dim3(B_*NC, NH), 256, 0, stream>>>(xc, dtb, acs, S0, pv, Dp, Ybuf);
  k_rms     <<<dim3(M_), 256, 0, stream>>>(zx, Ybuf, rms_w, ynorm);
  k_gemm_out<<<dim3(128, 4), 256, 0, stream>>>(ynorm, W_out, out);
  k_gn      <<<dim3(B_, 8), 256, 0, stream>>>(gn_w, gn_b, out);
}

// Round 2
// 440.955 us; speedup vs baseline: 1.3959x; 1.3959x over previous
//
#include <hip/hip_runtime.h>
#include <hip/hip_bf16.h>
#include <math.h>

#define B_ 8
#define L_ 1024
#define DM 256
#define DI 512
#define HD 32
#define NH 16
#define DS 128
#define CDIM 768
#define NZX 1280    // z + xBC cols (dt computed separately)
#define CH 256
#define NC 4
#define M_ (B_*L_)
#define EPSV 1e-5f

typedef short bf16x8 __attribute__((ext_vector_type(8)));
typedef float f32x4 __attribute__((ext_vector_type(4)));

// ---- workspace layout (float units) ----
#define OFF_ZX   0                         // M_*NZX fp32
#define SZ_ZX    (M_*NZX)
#define OFF_XC   (OFF_ZX+SZ_ZX)            // M_*CDIM fp32
#define SZ_XC    (M_*CDIM)
#define OFF_DT   (OFF_XC+SZ_XC)            // M_*NH fp32
#define SZ_DT    (M_*NH)
#define OFF_ACS  (OFF_DT+SZ_DT)
#define SZ_ACS   (B_*NC*NH*CH)
#define OFF_S0   (OFF_ACS+SZ_ACS)
#define SZ_S0    (B_*NC*CH*CH)
#define OFF_ST   (OFF_S0+SZ_S0)
#define SZ_ST    (B_*NC*NH*HD*DS)
#define OFF_PV   (OFF_ST+SZ_ST)
#define SZ_PV    SZ_ST
#define OFF_Y    (OFF_PV+SZ_PV)
#define SZ_Y     (M_*DI)
#define OFF_YNB  (OFF_Y+SZ_Y)              // M_*DI bf16 = M_*DI/2 floats
#define SZ_YNB   (M_*DI/2)
#define OFF_XBF  (OFF_YNB+SZ_YNB)          // M_*DM bf16
#define SZ_XBF   (M_*DM/2)
#define OFF_WBF  (OFF_XBF+SZ_XBF)          // 1296*DM bf16
#define SZ_WBF   (1296*DM/2)
#define OFF_WOBF (OFF_WBF+SZ_WBF)          // DM*DI bf16
#define SZ_WOBF  (DM*DI/2)

__device__ __forceinline__ ushort f2bf(float v) {
  __hip_bfloat16 h = __float2bfloat16(v);
  return *(ushort*)&h;
}

// ---------- cast helpers ----------
__global__ void k_cast(const float* __restrict__ s, ushort* __restrict__ d, int n) {
  int i = blockIdx.x*256 + threadIdx.x;
  if (i < n) d[i] = f2bf(s[i]);
}

// transpose+cast x[b][k][l] -> xbf[m=b*L+l][k]
__global__ __launch_bounds__(256) void k_cast_x(const float* __restrict__ x,
                                                ushort* __restrict__ xbf) {
  __shared__ float Ts[64][65];
  const int k0 = blockIdx.x*64, l0 = blockIdx.y*64, b = blockIdx.z;
  const int t = threadIdx.x;
  for (int i = t; i < 4096; i += 256) {
    int kk = i>>6, ll = i&63;
    Ts[kk][ll] = x[(size_t)b*DM*L_ + (size_t)(k0+kk)*L_ + l0+ll];
  }
  __syncthreads();
  for (int i = t; i < 4096; i += 256) {
    int mm = i>>6, kk = i&63;
    xbf[(size_t)(b*L_ + l0+mm)*DM + k0+kk] = f2bf(Ts[kk][mm]);
  }
}

// ---------- in-proj GEMM (bf16 MFMA): zx[m][n] = sum_k xbf[m][k]*wbf[n][k] ----------
__global__ __launch_bounds__(256) void k_gemm_in_mfma(const ushort* __restrict__ xbf,
                                                      const ushort* __restrict__ wbf,
                                                      float* __restrict__ zx) {
  __shared__ ushort As[128*40];
  __shared__ ushort Bs[64*40];
  const int tid = threadIdx.x;
  const int n0 = blockIdx.x*64, m0 = blockIdx.y*128;
  const int wave = tid>>6, lane = tid&63;
  const int lr = lane&15, quad = lane>>4;
  const int KK = DM;
  f32x4 acc[2][4];
#pragma unroll
  for (int mi=0;mi<2;++mi)
#pragma unroll
    for (int ni=0;ni<4;++ni)
#pragma unroll
      for (int r=0;r<4;++r) acc[mi][ni][r] = 0.f;
  const int srow = tid>>2, sc = tid&3;
  for (int k0 = 0; k0 < KK; k0 += 32) {
    *(uint4*)&As[srow*40 + sc*8]      = *(const uint4*)(xbf + (size_t)(m0+srow)*KK    + k0 + sc*8);
    *(uint4*)&As[(srow+64)*40 + sc*8] = *(const uint4*)(xbf + (size_t)(m0+srow+64)*KK + k0 + sc*8);
    *(uint4*)&Bs[srow*40 + sc*8]      = *(const uint4*)(wbf + (size_t)(n0+srow)*KK    + k0 + sc*8);
    __syncthreads();
    bf16x8 af[2], bfr[4];
    const int ar = wave*32 + lr;
    af[0] = *(const bf16x8*)&As[ar*40 + quad*8];
    af[1] = *(const bf16x8*)&As[(ar+16)*40 + quad*8];
#pragma unroll
    for (int ni=0;ni<4;++ni) bfr[ni] = *(const bf16x8*)&Bs[(ni*16+lr)*40 + quad*8];
#pragma unroll
    for (int mi=0;mi<2;++mi)
#pragma unroll
      for (int ni=0;ni<4;++ni)
        acc[mi][ni] = __builtin_amdgcn_mfma_f32_16x16x32_bf16(af[mi], bfr[ni], acc[mi][ni], 0, 0, 0);
    __syncthreads();
  }
#pragma unroll
  for (int mi=0;mi<2;++mi) {
    int m = m0 + wave*32 + mi*16 + quad*4;
#pragma unroll
    for (int ni=0;ni<4;++ni) {
      int n = n0 + ni*16 + lr;
#pragma unroll
      for (int r=0;r<4;++r) zx[(size_t)(m+r)*NZX + n] = acc[mi][ni][r];
    }
  }
}

// ---------- dt in exact fp32: dt[m][h] = softplus(x[m,:]·W_in[1280+h,:] + dt_bias[h]) ----------
__global__ __launch_bounds__(256) void k_dt_direct(const float* __restrict__ x,
                                                   const float* __restrict__ W,
                                                   const float* __restrict__ dt_bias,
                                                   float* __restrict__ dtb) {
  __shared__ float Xs[256][16];
  __shared__ float Ws[16][257];
  const int t = threadIdx.x;
  const int bm = blockIdx.x*16;          // 16 m-rows, same batch
  const int b = bm >> 10, l0 = bm & 1023;
  for (int i = t; i < 4096; i += 256) {
    int h = i>>8, k = i&255;
    Ws[h][k] = W[(size_t)(NZX+h)*DM + k];
  }
  for (int i = t; i < 4096; i += 256) {
    int k = i>>4, li = i&15;
    Xs[k][li] = x[(size_t)b*DM*L_ + (size_t)k*L_ + l0+li];
  }
  __syncthreads();
  const int h = t&15, li = t>>4;
  float acc = 0.f;
#pragma unroll 8
  for (int k = 0; k < 256; ++k) acc += Xs[k][li]*Ws[h][k];
  float v = acc + dt_bias[h];
  dtb[(size_t)bm*NH + t] = (v > 20.f) ? v : log1pf(expf(v));
}

// ---------- conv4 + SiLU ----------
__global__ void k_conv(const float* __restrict__ zx, const float* __restrict__ cw,
                       const float* __restrict__ cb, float* __restrict__ xc) {
  int j = blockIdx.x*256 + threadIdx.x;
  int m = blockIdx.y;
  if (j >= CDIM) return;
  int l = m & 1023;
  int mb = m - l;
  float acc = cb[j];
#pragma unroll
  for (int k = 0; k < 4; ++k) {
    int ll = l - 3 + k;
    if (ll >= 0) acc += cw[j*4+k] * zx[(size_t)(mb+ll)*NZX + DI + j];
  }
  acc = acc / (1.f + expf(-acc));
  xc[(size_t)m*CDIM + j] = acc;
}

// ---------- S0 = Cm·Bm^T ----------
__global__ __launch_bounds__(256) void k_s0(const float* __restrict__ xc,
                                            float* __restrict__ S0) {
  __shared__ float As[16][65];
  __shared__ float Bs[16][65];
  const int tid = threadIdx.x;
  const int l0 = blockIdx.x * 64;
  const int s0 = blockIdx.y * 64;
  const int bc = blockIdx.z;
  const int base = bc * CH;
  const int tr = tid >> 4, tc = tid & 15;
  float acc[4][4] = {};
  for (int k0 = 0; k0 < DS; k0 += 16) {
    for (int i = tid; i < 1024; i += 256) {
      int mm = i >> 4, kk = i & 15;
      As[kk][mm] = xc[(size_t)(base+l0+mm)*CDIM + (DI+DS) + k0 + kk];
      Bs[kk][mm] = xc[(size_t)(base+s0+mm)*CDIM + DI + k0 + kk];
    }
    __syncthreads();
#pragma unroll
    for (int k = 0; k < 16; ++k) {
      float a[4], bb[4];
#pragma unroll
      for (int i = 0; i < 4; ++i) a[i] = As[k][tr*4+i];
#pragma unroll
      for (int j = 0; j < 4; ++j) bb[j] = Bs[k][tc*4+j];
#pragma unroll
      for (int i = 0; i < 4; ++i)
#pragma unroll
        for (int j = 0; j < 4; ++j) acc[i][j] += a[i]*bb[j];
    }
    __syncthreads();
  }
  for (int i = 0; i < 4; ++i)
    for (int j = 0; j < 4; ++j)
      S0[((size_t)bc*CH + l0+tr*4+i)*CH + s0+tc*4+j] = acc[i][j];
}

// ---------- per (b,c,h): cumsum(dt*A) + chunk states ----------
__global__ __launch_bounds__(256) void k_states(const float* __restrict__ xc,
                                                const float* __restrict__ dtb,
                                                const float* __restrict__ A_log,
                                                float* __restrict__ acs_g,
                                                float* __restrict__ st) {
  __shared__ float Xs[CH][HD+1];
  __shared__ float acs[CH];
  __shared__ float wv[CH];
  const int t = threadIdx.x;
  const int bc = blockIdx.x, h = blockIdx.y;
  const int base = bc * CH;
  float dt_t = dtb[(size_t)(base+t)*NH + h];
  float An = -expf(A_log[h]);
  acs[t] = dt_t * An;
  for (int i = t; i < CH*HD; i += 256) {
    int l = i >> 5, p = i & 31;
    Xs[l][p] = xc[(size_t)(base+l)*CDIM + h*HD + p];
  }
  __syncthreads();
  for (int off = 1; off < CH; off <<= 1) {
    float v = (t >= off) ? acs[t-off] : 0.f;
    __syncthreads();
    acs[t] += v;
    __syncthreads();
  }
  float alast = acs[CH-1];
  acs_g[((size_t)bc*NH + h)*CH + t] = acs[t];
  wv[t] = expf(alast - acs[t]) * dt_t;
  __syncthreads();
  const int n = t & 127, ph = t >> 7;
  float acc[16];
#pragma unroll
  for (int i = 0; i < 16; ++i) acc[i] = 0.f;
  for (int l = 0; l < CH; ++l) {
    float bw = xc[(size_t)(base+l)*CDIM + DI + n] * wv[l];
#pragma unroll
    for (int i = 0; i < 16; ++i) acc[i] += bw * Xs[l][ph*16+i];
  }
  size_t sb = ((size_t)bc*NH + h)*HD*DS;
  for (int i = 0; i < 16; ++i) st[sb + (size_t)(ph*16+i)*DS + n] = acc[i];
}

// ---------- inter-chunk scan ----------
__global__ void k_scan(const float* __restrict__ acs_g, const float* __restrict__ st,
                       float* __restrict__ pv) {
  const int b = blockIdx.x, h = blockIdx.y;
  const int t = threadIdx.x;
  float P[16];
#pragma unroll
  for (int i = 0; i < 16; ++i) P[i] = 0.f;
  for (int c = 0; c < NC; ++c) {
    size_t sb = ((size_t)(b*NC+c)*NH + h)*HD*DS;
    float T = acs_g[((size_t)(b*NC+c)*NH + h)*CH + (CH-1)];
    float ec = expf(T);
#pragma unroll
    for (int i = 0; i < 16; ++i) {
      size_t e = sb + (size_t)i*256 + t;
      pv[e] = P[i];
      P[i] = st[e] + ec * P[i];
    }
  }
}

// ---------- Y = Y_diag + Y_off + D*xs ----------
__global__ __launch_bounds__(256) void k_y(const float* __restrict__ xc,
                                           const float* __restrict__ dtb,
                                           const float* __restrict__ acs_g,
                                           const float* __restrict__ S0,
                                           const float* __restrict__ pv,
                                           const float* __restrict__ Dp,
                                           float* __restrict__ Y) {
  __shared__ float Xs[CH][HD+1];
  __shared__ float prevS[HD][DS+1];
  __shared__ float acs[CH];
  __shared__ float dts[CH];
  const int t = threadIdx.x;
  const int bc = blockIdx.x, h = blockIdx.y;
  const int base = bc * CH;
  for (int i = t; i < CH*HD; i += 256) {
    int l = i >> 5, p = i & 31;
    Xs[l][p] = xc[(size_t)(base+l)*CDIM + h*HD + p];
  }
  size_t pb = ((size_t)bc*NH + h)*HD*DS;
  for (int i = t; i < HD*DS; i += 256) prevS[i>>7][i&127] = pv[pb + i];
  acs[t] = acs_g[((size_t)bc*NH + h)*CH + t];
  dts[t] = dtb[(size_t)(base+t)*NH + h];
  __syncthreads();
  const int l = t;
  float acc[HD];
#pragma unroll
  for (int p = 0; p < HD; ++p) acc[p] = 0.f;
  for (int n = 0; n < DS; ++n) {
    float cv = xc[(size_t)(base+l)*CDIM + (DI+DS) + n];
#pragma unroll
    for (int p = 0; p < HD; ++p) acc[p] += cv * prevS[p][n];
  }
  float eA = expf(acs[l]);
#pragma unroll
  for (int p = 0; p < HD; ++p) acc[p] *= eA;
  const int wlim = ((t >> 6) + 1) * 64;
  const float* srow = S0 + (size_t)(bc*CH + l)*CH;
  for (int s = 0; s < wlim; ++s) {
    float d = (s <= l) ? (acs[l] - acs[s]) : -1e30f;
    float sc = srow[s] * expf(d) * dts[s];
#pragma unroll
    for (int p = 0; p < HD; ++p) acc[p] += sc * Xs[s][p];
  }
  float dph = Dp[h];
  size_t ob = (size_t)(base+l)*DI + h*HD;
#pragma unroll
  for (int p = 0; p < HD; ++p) Y[ob+p] = acc[p] + dph * Xs[l][p];
}

// ---------- gate + RMSNorm, write bf16 ----------
__global__ __launch_bounds__(256) void k_rms(const float* __restrict__ zx,
                                             const float* __restrict__ Y,
                                             const float* __restrict__ rw,
                                             ushort* __restrict__ yn) {
  const int m = blockIdx.x, t = threadIdx.x;
  float z0 = zx[(size_t)m*NZX + t];
  float z1 = zx[(size_t)m*NZX + t + 256];
  float y0 = Y[(size_t)m*DI + t]       * z0 / (1.f + expf(-z0));
  float y1 = Y[(size_t)m*DI + t + 256] * z1 / (1.f + expf(-z1));
  float ss = y0*y0 + y1*y1;
#pragma unroll
  for (int off = 32; off > 0; off >>= 1) ss += __shfl_down(ss, off);
  __shared__ float red[4];
  __shared__ float sinv;
  if ((t & 63) == 0) red[t >> 6] = ss;
  __syncthreads();
  if (t == 0) sinv = rsqrtf((red[0]+red[1]+red[2]+red[3]) * (1.f/DI) + EPSV);
  __syncthreads();
  float inv = sinv;
  yn[(size_t)m*DI + t]       = f2bf(y0 * inv * rw[t]);
  yn[(size_t)m*DI + t + 256] = f2bf(y1 * inv * rw[t+256]);
}

// ---------- out-proj GEMM (bf16 MFMA), store transposed (B, DM, L) ----------
__global__ __launch_bounds__(256) void k_gemm_out_mfma(const ushort* __restrict__ ynbf,
                                                       const ushort* __restrict__ wobf,
                                                       float* __restrict__ outp) {
  __shared__ ushort As[128*40];
  __shared__ ushort Bs[64*40];
  const int tid = threadIdx.x;
  const int n0 = blockIdx.x*64, m0 = blockIdx.y*128;
  const int wave = tid>>6, lane = tid&63;
  const int lr = lane&15, quad = lane>>4;
  const int KK = DI;
  f32x4 acc[2][4];
#pragma unroll
  for (int mi=0;mi<2;++mi)
#pragma unroll
    for (int ni=0;ni<4;++ni)
#pragma unroll
      for (int r=0;r<4;++r) acc[mi][ni][r] = 0.f;
  const int srow = tid>>2, sc = tid&3;
  for (int k0 = 0; k0 < KK; k0 += 32) {
    *(uint4*)&As[srow*40 + sc*8]      = *(const uint4*)(ynbf + (size_t)(m0+srow)*KK    + k0 + sc*8);
    *(uint4*)&As[(srow+64)*40 + sc*8] = *(const uint4*)(ynbf + (size_t)(m0+srow+64)*KK + k0 + sc*8);
    *(uint4*)&Bs[srow*40 + sc*8]      = *(const uint4*)(wobf + (size_t)(n0+srow)*KK    + k0 + sc*8);
    __syncthreads();
    bf16x8 af[2], bfr[4];
    const int ar = wave*32 + lr;
    af[0] = *(const bf16x8*)&As[ar*40 + quad*8];
    af[1] = *(const bf16x8*)&As[(ar+16)*40 + quad*8];
#pragma unroll
    for (int ni=0;ni<4;++ni) bfr[ni] = *(const bf16x8*)&Bs[(ni*16+lr)*40 + quad*8];
#pragma unroll
    for (int mi=0;mi<2;++mi)
#pragma unroll
      for (int ni=0;ni<4;++ni)
        acc[mi][ni] = __builtin_amdgcn_mfma_f32_16x16x32_bf16(af[mi], bfr[ni], acc[mi][ni], 0, 0, 0);
    __syncthreads();
  }
  const int b = m0 >> 10, l0 = m0 & 1023;
#pragma unroll
  for (int mi=0;mi<2;++mi) {
    int lb = l0 + wave*32 + mi*16 + quad*4;
#pragma unroll
    for (int ni=0;ni<4;++ni) {
      int n = n0 + ni*16 + lr;
      float4 v = make_float4(acc[mi][ni][0], acc[mi][ni][1], acc[mi][ni][2], acc[mi][ni][3]);
      *(float4*)&outp[(size_t)b*DM*L_ + (size_t)n*L_ + lb] = v;
    }
  }
}

// ---------- GroupNorm + Mish ----------
__global__ __launch_bounds__(256) void k_gn(const float* __restrict__ gw,
                                            const float* __restrict__ gb,
                                            float* __restrict__ o) {
  const int b = blockIdx.x, g = blockIdx.y;
  const int t = threadIdx.x;
  size_t base = (size_t)b*DM*L_ + (size_t)g*32*L_;
  float s = 0.f, ss = 0.f;
  for (int i = t; i < 32*L_; i += 256) {
    float v = o[base+i];
    s += v; ss += v*v;
  }
#pragma unroll
  for (int off = 32; off > 0; off >>= 1) { s += __shfl_down(s, off); ss += __shfl_down(ss, off); }
  __shared__ float rs[4], rss[4];
  __shared__ float smean, sinv;
  if ((t & 63) == 0) { rs[t>>6] = s; rss[t>>6] = ss; }
  __syncthreads();
  if (t == 0) {
    float S = rs[0]+rs[1]+rs[2]+rs[3];
    float SS = rss[0]+rss[1]+rss[2]+rss[3];
    float mean = S * (1.f/(32.f*L_));
    float var  = SS * (1.f/(32.f*L_)) - mean*mean;
    smean = mean; sinv = rsqrtf(var + EPSV);
  }
  __syncthreads();
  float mean = smean, inv = sinv;
  for (int i = t; i < 32*L_; i += 256) {
    int ch = g*32 + (i >> 10);
    float v = (o[base+i] - mean) * inv * gw[ch] + gb[ch];
    float sp = (v > 20.f) ? v : log1pf(expf(v));
    o[base+i] = v * tanhf(sp);
  }
}

extern "C" void kernel_launch(void* const* d_in, const int* in_sizes, int n_in,
                              void* d_out, int out_size, void* d_ws, size_t ws_size,
                              hipStream_t stream) {
  const float* x       = (const float*)d_in[0];
  const float* W_in    = (const float*)d_in[1];
  const float* conv_w  = (const float*)d_in[2];
  const float* conv_b  = (const float*)d_in[3];
  const float* dt_bias = (const float*)d_in[4];
  const float* A_log   = (const float*)d_in[5];
  const float* Dp      = (const float*)d_in[6];
  const float* rms_w   = (const float*)d_in[7];
  const float* W_out   = (const float*)d_in[8];
  const float* gn_w    = (const float*)d_in[9];
  const float* gn_b    = (const float*)d_in[10];
  float* out = (float*)d_out;
  float* ws  = (float*)d_ws;

  float*  zx    = ws + OFF_ZX;
  float*  xc    = ws + OFF_XC;
  float*  dtb   = ws + OFF_DT;
  float*  acs   = ws + OFF_ACS;
  float*  S0    = ws + OFF_S0;
  float*  st    = ws + OFF_ST;
  float*  pv    = ws + OFF_PV;
  float*  Ybuf  = ws + OFF_Y;
  ushort* ynbf  = (ushort*)(ws + OFF_YNB);
  ushort* xbf   = (ushort*)(ws + OFF_XBF);
  ushort* wbf   = (ushort*)(ws + OFF_WBF);
  ushort* wobf  = (ushort*)(ws + OFF_WOBF);

  k_cast_x       <<<dim3(4, 16, 8), 256, 0, stream>>>(x, xbf);
  k_cast         <<<dim3((1296*DM+255)/256), 256, 0, stream>>>(W_in, wbf, 1296*DM);
  k_cast         <<<dim3((DM*DI+255)/256), 256, 0, stream>>>(W_out, wobf, DM*DI);
  k_gemm_in_mfma <<<dim3(NZX/64, M_/128), 256, 0, stream>>>(xbf, wbf, zx);
  k_dt_direct    <<<dim3(M_/16), 256, 0, stream>>>(x, W_in, dt_bias, dtb);
  k_conv         <<<dim3(3, M_), 256, 0, stream>>>(zx, conv_w, conv_b, xc);
  k_s0           <<<dim3(4, 4, B_*NC), 256, 0, stream>>>(xc, S0);
  k_states       <<<dim3(B_*NC, NH), 256, 0, stream>>>(xc, dtb, A_log, acs, st);
  k_scan         <<<dim3(B_, NH), 256, 0, stream>>>(acs, st, pv);
  k_y            <<<dim3(B_*NC, NH), 256, 0, stream>>>(xc, dtb, acs, S0, pv, Dp, Ybuf);
  k_rms          <<<dim3(M_), 256, 0, stream>>>(zx, Ybuf, rms_w, ynbf);
  k_gemm_out_mfma<<<dim3(DM/64, M_/128), 256, 0, stream>>>(ynbf, wobf, out);
  k_gn           <<<dim3(B_, 8), 256, 0, stream>>>(gn_w, gn_b, out);
}

// Round 3
// 347.370 us; speedup vs baseline: 1.7720x; 1.2694x over previous
//
#include <hip/hip_runtime.h>
#include <hip/hip_bf16.h>
#include <math.h>

#define B_ 8
#define L_ 1024
#define DM 256
#define DI 512
#define HD 32
#define NH 16
#define DS 128
#define CDIM 768
#define NZX 1280    // z + xBC cols (dt computed separately)
#define CH 256
#define NC 4
#define M_ (B_*L_)
#define EPSV 1e-5f

typedef short bf16x8 __attribute__((ext_vector_type(8)));
typedef float f32x4 __attribute__((ext_vector_type(4)));

// ---- workspace layout (float units) ----
#define OFF_ZX   0                         // M_*NZX fp32
#define SZ_ZX    (M_*NZX)
#define OFF_XC   (OFF_ZX+SZ_ZX)            // M_*CDIM bf16 (ushort) -> M_*CDIM/2 floats
#define SZ_XC    (M_*CDIM/2)
#define OFF_DT   (OFF_XC+SZ_XC)            // M_*NH fp32
#define SZ_DT    (M_*NH)
#define OFF_ACS  (OFF_DT+SZ_DT)
#define SZ_ACS   (B_*NC*NH*CH)
#define OFF_S0   (OFF_ACS+SZ_ACS)          // bf16 S0b: B_*NC*CH*CH ushorts
#define SZ_S0    (B_*NC*CH*CH/2)
#define OFF_ST   (OFF_S0+SZ_S0)
#define SZ_ST    (B_*NC*NH*HD*DS)
#define OFF_PV   (OFF_ST+SZ_ST)
#define SZ_PV    SZ_ST
#define OFF_Y    (OFF_PV+SZ_PV)
#define SZ_Y     (M_*DI)
#define OFF_YNB  (OFF_Y+SZ_Y)              // M_*DI bf16
#define SZ_YNB   (M_*DI/2)
#define OFF_XBF  (OFF_YNB+SZ_YNB)          // M_*DM bf16
#define SZ_XBF   (M_*DM/2)
#define OFF_WBF  (OFF_XBF+SZ_XBF)          // 1296*DM bf16
#define SZ_WBF   (1296*DM/2)
#define OFF_WOBF (OFF_WBF+SZ_WBF)          // DM*DI bf16
#define SZ_WOBF  (DM*DI/2)

__device__ __forceinline__ ushort f2bf(float v) {
  __hip_bfloat16 h = __float2bfloat16(v);
  return *(ushort*)&h;
}
__device__ __forceinline__ float bf2f(ushort u) {
  return __uint_as_float(((unsigned int)u) << 16);
}

// ---------- cast helpers ----------
__global__ void k_cast(const float* __restrict__ s, ushort* __restrict__ d, int n) {
  int i = blockIdx.x*256 + threadIdx.x;
  if (i < n) d[i] = f2bf(s[i]);
}

// transpose+cast x[b][k][l] -> xbf[m=b*L+l][k]
__global__ __launch_bounds__(256) void k_cast_x(const float* __restrict__ x,
                                                ushort* __restrict__ xbf) {
  __shared__ float Ts[64][65];
  const int k0 = blockIdx.x*64, l0 = blockIdx.y*64, b = blockIdx.z;
  const int t = threadIdx.x;
  for (int i = t; i < 4096; i += 256) {
    int kk = i>>6, ll = i&63;
    Ts[kk][ll] = x[(size_t)b*DM*L_ + (size_t)(k0+kk)*L_ + l0+ll];
  }
  __syncthreads();
  for (int i = t; i < 4096; i += 256) {
    int mm = i>>6, kk = i&63;
    xbf[(size_t)(b*L_ + l0+mm)*DM + k0+kk] = f2bf(Ts[kk][mm]);
  }
}

// ---------- in-proj GEMM (bf16 MFMA) ----------
__global__ __launch_bounds__(256) void k_gemm_in_mfma(const ushort* __restrict__ xbf,
                                                      const ushort* __restrict__ wbf,
                                                      float* __restrict__ zx) {
  __shared__ ushort As[128*40];
  __shared__ ushort Bs[64*40];
  const int tid = threadIdx.x;
  const int n0 = blockIdx.x*64, m0 = blockIdx.y*128;
  const int wave = tid>>6, lane = tid&63;
  const int lr = lane&15, quad = lane>>4;
  const int KK = DM;
  f32x4 acc[2][4];
#pragma unroll
  for (int mi=0;mi<2;++mi)
#pragma unroll
    for (int ni=0;ni<4;++ni)
#pragma unroll
      for (int r=0;r<4;++r) acc[mi][ni][r] = 0.f;
  const int srow = tid>>2, sc = tid&3;
  for (int k0 = 0; k0 < KK; k0 += 32) {
    *(uint4*)&As[srow*40 + sc*8]      = *(const uint4*)(xbf + (size_t)(m0+srow)*KK    + k0 + sc*8);
    *(uint4*)&As[(srow+64)*40 + sc*8] = *(const uint4*)(xbf + (size_t)(m0+srow+64)*KK + k0 + sc*8);
    *(uint4*)&Bs[srow*40 + sc*8]      = *(const uint4*)(wbf + (size_t)(n0+srow)*KK    + k0 + sc*8);
    __syncthreads();
    bf16x8 af[2], bfr[4];
    const int ar = wave*32 + lr;
    af[0] = *(const bf16x8*)&As[ar*40 + quad*8];
    af[1] = *(const bf16x8*)&As[(ar+16)*40 + quad*8];
#pragma unroll
    for (int ni=0;ni<4;++ni) bfr[ni] = *(const bf16x8*)&Bs[(ni*16+lr)*40 + quad*8];
#pragma unroll
    for (int mi=0;mi<2;++mi)
#pragma unroll
      for (int ni=0;ni<4;++ni)
        acc[mi][ni] = __builtin_amdgcn_mfma_f32_16x16x32_bf16(af[mi], bfr[ni], acc[mi][ni], 0, 0, 0);
    __syncthreads();
  }
#pragma unroll
  for (int mi=0;mi<2;++mi) {
    int m = m0 + wave*32 + mi*16 + quad*4;
#pragma unroll
    for (int ni=0;ni<4;++ni) {
      int n = n0 + ni*16 + lr;
#pragma unroll
      for (int r=0;r<4;++r) zx[(size_t)(m+r)*NZX + n] = acc[mi][ni][r];
    }
  }
}

// ---------- dt exact fp32 ----------
__global__ __launch_bounds__(256) void k_dt_direct(const float* __restrict__ x,
                                                   const float* __restrict__ W,
                                                   const float* __restrict__ dt_bias,
                                                   float* __restrict__ dtb) {
  __shared__ float Xs[256][16];
  __shared__ float Ws[16][257];
  const int t = threadIdx.x;
  const int bm = blockIdx.x*16;
  const int b = bm >> 10, l0 = bm & 1023;
  for (int i = t; i < 4096; i += 256) {
    int h = i>>8, k = i&255;
    Ws[h][k] = W[(size_t)(NZX+h)*DM + k];
  }
  for (int i = t; i < 4096; i += 256) {
    int k = i>>4, li = i&15;
    Xs[k][li] = x[(size_t)b*DM*L_ + (size_t)k*L_ + l0+li];
  }
  __syncthreads();
  const int h = t&15, li = t>>4;
  float acc = 0.f;
#pragma unroll 8
  for (int k = 0; k < 256; ++k) acc += Xs[k][li]*Ws[h][k];
  float v = acc + dt_bias[h];
  dtb[(size_t)bm*NH + t] = (v > 20.f) ? v : log1pf(expf(v));
}

// ---------- conv4 + SiLU -> bf16 xcb ----------
__global__ void k_conv(const float* __restrict__ zx, const float* __restrict__ cw,
                       const float* __restrict__ cb, ushort* __restrict__ xcb) {
  int j = blockIdx.x*256 + threadIdx.x;
  int m = blockIdx.y;
  if (j >= CDIM) return;
  int l = m & 1023;
  int mb = m - l;
  float acc = cb[j];
#pragma unroll
  for (int k = 0; k < 4; ++k) {
    int ll = l - 3 + k;
    if (ll >= 0) acc += cw[j*4+k] * zx[(size_t)(mb+ll)*NZX + DI + j];
  }
  acc = acc / (1.f + expf(-acc));
  xcb[(size_t)m*CDIM + j] = f2bf(acc);
}

// ---------- S0b = Cm·Bm^T (bf16 MFMA, lower-triangular tiles only) ----------
__global__ __launch_bounds__(256) void k_s0_mfma(const ushort* __restrict__ xcb,
                                                 ushort* __restrict__ S0b) {
  const int lt = blockIdx.x, st = blockIdx.y, bc = blockIdx.z;
  if (st > lt) return;
  const int base = bc*CH;
  const int t = threadIdx.x;
  const int wave = t>>6, lane = t&63, lr = lane&15, quad = lane>>4;
  const int l = lt*64 + wave*16 + lr;
  f32x4 acc[4];
#pragma unroll
  for (int nt = 0; nt < 4; ++nt)
#pragma unroll
    for (int r = 0; r < 4; ++r) acc[nt][r] = 0.f;
#pragma unroll
  for (int ks = 0; ks < 4; ++ks) {
    bf16x8 af = *(const bf16x8*)(xcb + (size_t)(base+l)*CDIM + (DI+DS) + ks*32 + quad*8);
#pragma unroll
    for (int nt = 0; nt < 4; ++nt) {
      bf16x8 bf = *(const bf16x8*)(xcb + (size_t)(base + st*64 + nt*16 + lr)*CDIM + DI + ks*32 + quad*8);
      acc[nt] = __builtin_amdgcn_mfma_f32_16x16x32_bf16(af, bf, acc[nt], 0, 0, 0);
    }
  }
#pragma unroll
  for (int nt = 0; nt < 4; ++nt)
#pragma unroll
    for (int r = 0; r < 4; ++r)
      S0b[((size_t)bc*CH + lt*64 + wave*16 + quad*4 + r)*CH + st*64 + nt*16 + lr] = f2bf(acc[nt][r]);
}

// ---------- per (b,c,h): cumsum(dt*A) + chunk states ----------
__global__ __launch_bounds__(256) void k_states(const ushort* __restrict__ xcb,
                                                const float* __restrict__ dtb,
                                                const float* __restrict__ A_log,
                                                float* __restrict__ acs_g,
                                                float* __restrict__ st) {
  __shared__ float Xs[CH][HD+1];
  __shared__ float acs[CH];
  __shared__ float wv[CH];
  const int t = threadIdx.x;
  const int bc = blockIdx.x, h = blockIdx.y;
  const int base = bc * CH;
  float dt_t = dtb[(size_t)(base+t)*NH + h];
  float An = -expf(A_log[h]);
  acs[t] = dt_t * An;
  for (int i = t; i < CH*HD; i += 256) {
    int l = i >> 5, p = i & 31;
    Xs[l][p] = bf2f(xcb[(size_t)(base+l)*CDIM + h*HD + p]);
  }
  __syncthreads();
  for (int off = 1; off < CH; off <<= 1) {
    float v = (t >= off) ? acs[t-off] : 0.f;
    __syncthreads();
    acs[t] += v;
    __syncthreads();
  }
  float alast = acs[CH-1];
  acs_g[((size_t)bc*NH + h)*CH + t] = acs[t];
  wv[t] = expf(alast - acs[t]) * dt_t;
  __syncthreads();
  const int n = t & 127, ph = t >> 7;
  float acc[16];
#pragma unroll
  for (int i = 0; i < 16; ++i) acc[i] = 0.f;
  for (int l = 0; l < CH; ++l) {
    float bw = bf2f(xcb[(size_t)(base+l)*CDIM + DI + n]) * wv[l];
#pragma unroll
    for (int i = 0; i < 16; ++i) acc[i] += bw * Xs[l][ph*16+i];
  }
  size_t sb = ((size_t)bc*NH + h)*HD*DS;
  for (int i = 0; i < 16; ++i) st[sb + (size_t)(ph*16+i)*DS + n] = acc[i];
}

// ---------- inter-chunk scan ----------
__global__ void k_scan(const float* __restrict__ acs_g, const float* __restrict__ st,
                       float* __restrict__ pv) {
  const int b = blockIdx.x, h = blockIdx.y;
  const int t = threadIdx.x;
  float P[16];
#pragma unroll
  for (int i = 0; i < 16; ++i) P[i] = 0.f;
  for (int c = 0; c < NC; ++c) {
    size_t sb = ((size_t)(b*NC+c)*NH + h)*HD*DS;
    float T = acs_g[((size_t)(b*NC+c)*NH + h)*CH + (CH-1)];
    float ec = expf(T);
#pragma unroll
    for (int i = 0; i < 16; ++i) {
      size_t e = sb + (size_t)i*256 + t;
      pv[e] = P[i];
      P[i] = st[e] + ec * P[i];
    }
  }
}

// ---------- Y = Y_diag + Y_off + D*xs (MFMA) ----------
__global__ __launch_bounds__(256) void k_y_mfma(const ushort* __restrict__ xcb,
    const float* __restrict__ dtb, const float* __restrict__ acs_g,
    const ushort* __restrict__ S0b, const float* __restrict__ pv,
    const float* __restrict__ Dp, float* __restrict__ Y) {
  __shared__ ushort Xt[32][280];     // X^T bf16, row stride 280 (16B-aligned)
  __shared__ float acs[CH];
  __shared__ float dts[CH];
  __shared__ float E8[CH];
  const int t = threadIdx.x;
  const int bc = blockIdx.x, h = blockIdx.y;
  const int base = bc*CH;
  acs[t] = acs_g[((size_t)bc*NH + h)*CH + t];
  dts[t] = dtb[(size_t)(base+t)*NH + h];
  {
    const ushort* xp = xcb + (size_t)(base+t)*CDIM + h*HD;
    ushort tmp[32];
    *(uint4*)&tmp[0]  = *(const uint4*)(xp);
    *(uint4*)&tmp[8]  = *(const uint4*)(xp+8);
    *(uint4*)&tmp[16] = *(const uint4*)(xp+16);
    *(uint4*)&tmp[24] = *(const uint4*)(xp+24);
#pragma unroll
    for (int p = 0; p < 32; ++p) Xt[p][t] = tmp[p];
  }
  __syncthreads();
  E8[t] = expf(acs[t & ~7] - acs[t]) * dts[t];
  __syncthreads();
  const int wave = t>>6, lane = t&63, lr = lane&15, quad = lane>>4;
  f32x4 acc[4][2];
#pragma unroll
  for (int mt=0;mt<4;++mt)
#pragma unroll
    for (int nt=0;nt<2;++nt)
#pragma unroll
      for (int r=0;r<4;++r) acc[mt][nt][r] = 0.f;
  const size_t pb = ((size_t)bc*NH + h)*HD*DS;
  // ---- Y_off: C @ prev^T ----
#pragma unroll
  for (int ks = 0; ks < 4; ++ks) {
    bf16x8 bfr[2];
#pragma unroll
    for (int nt = 0; nt < 2; ++nt) {
      const float* pp = pv + pb + (size_t)(nt*16+lr)*DS + ks*32 + quad*8;
      float4 v0 = *(const float4*)pp;
      float4 v1 = *(const float4*)(pp+4);
      bf16x8 bb;
      bb[0]=(short)f2bf(v0.x); bb[1]=(short)f2bf(v0.y); bb[2]=(short)f2bf(v0.z); bb[3]=(short)f2bf(v0.w);
      bb[4]=(short)f2bf(v1.x); bb[5]=(short)f2bf(v1.y); bb[6]=(short)f2bf(v1.z); bb[7]=(short)f2bf(v1.w);
      bfr[nt] = bb;
    }
#pragma unroll
    for (int mt = 0; mt < 4; ++mt) {
      int l = wave*64 + mt*16 + lr;
      bf16x8 af = *(const bf16x8*)(xcb + (size_t)(base+l)*CDIM + (DI+DS) + ks*32 + quad*8);
      acc[mt][0] = __builtin_amdgcn_mfma_f32_16x16x32_bf16(af, bfr[0], acc[mt][0], 0,0,0);
      acc[mt][1] = __builtin_amdgcn_mfma_f32_16x16x32_bf16(af, bfr[1], acc[mt][1], 0,0,0);
    }
  }
  // scale Y_off rows by exp(acs[l])
#pragma unroll
  for (int mt = 0; mt < 4; ++mt)
#pragma unroll
    for (int r = 0; r < 4; ++r) {
      float e = expf(acs[wave*64 + mt*16 + quad*4 + r]);
      acc[mt][0][r] *= e;
      acc[mt][1][r] *= e;
    }
  // ---- Y_diag: masked M @ X^T ----
  float al[4];
#pragma unroll
  for (int mt = 0; mt < 4; ++mt) al[mt] = acs[wave*64 + mt*16 + lr];
  const int km3 = 2*wave + 1;     // kmax for mt=3
  for (int ks = 0; ks <= km3; ++ks) {
    const int sq = ks*32 + quad*8;
    const float as0 = acs[sq];
    const float4 e0 = *(const float4*)&E8[sq];
    const float4 e1 = *(const float4*)&E8[sq+4];
    const bf16x8 xb0 = *(const bf16x8*)&Xt[lr][sq];
    const bf16x8 xb1 = *(const bf16x8*)&Xt[16+lr][sq];
    const float ev[8] = {e0.x,e0.y,e0.z,e0.w,e1.x,e1.y,e1.z,e1.w};
#pragma unroll
    for (int mt = 0; mt < 4; ++mt) {
      if (ks > ((wave*64 + mt*16 + 15) >> 5)) continue;   // wave-uniform
      const int l = wave*64 + mt*16 + lr;
      const bf16x8 sb = *(const bf16x8*)(S0b + ((size_t)bc*CH + l)*CH + sq);
      const float el = expf(al[mt] - as0);
      bf16x8 mf;
#pragma unroll
      for (int j = 0; j < 8; ++j) {
        float v = (sq + j <= l) ? bf2f((ushort)sb[j]) * el * ev[j] : 0.f;
        mf[j] = (short)f2bf(v);
      }
      acc[mt][0] = __builtin_amdgcn_mfma_f32_16x16x32_bf16(mf, xb0, acc[mt][0], 0,0,0);
      acc[mt][1] = __builtin_amdgcn_mfma_f32_16x16x32_bf16(mf, xb1, acc[mt][1], 0,0,0);
    }
  }
  // ---- skip term + store ----
  const float dph = Dp[h];
#pragma unroll
  for (int mt = 0; mt < 4; ++mt) {
    const int lb = wave*64 + mt*16 + quad*4;
#pragma unroll
    for (int nt = 0; nt < 2; ++nt) {
      const int p = nt*16 + lr;
#pragma unroll
      for (int r = 0; r < 4; ++r) {
        float xv = bf2f(Xt[p][lb+r]);
        Y[(size_t)(base+lb+r)*DI + h*HD + p] = acc[mt][nt][r] + dph*xv;
      }
    }
  }
}

// ---------- gate + RMSNorm, write bf16 ----------
__global__ __launch_bounds__(256) void k_rms(const float* __restrict__ zx,
                                             const float* __restrict__ Y,
                                             const float* __restrict__ rw,
                                             ushort* __restrict__ yn) {
  const int m = blockIdx.x, t = threadIdx.x;
  float z0 = zx[(size_t)m*NZX + t];
  float z1 = zx[(size_t)m*NZX + t + 256];
  float y0 = Y[(size_t)m*DI + t]       * z0 / (1.f + expf(-z0));
  float y1 = Y[(size_t)m*DI + t + 256] * z1 / (1.f + expf(-z1));
  float ss = y0*y0 + y1*y1;
#pragma unroll
  for (int off = 32; off > 0; off >>= 1) ss += __shfl_down(ss, off);
  __shared__ float red[4];
  __shared__ float sinv;
  if ((t & 63) == 0) red[t >> 6] = ss;
  __syncthreads();
  if (t == 0) sinv = rsqrtf((red[0]+red[1]+red[2]+red[3]) * (1.f/DI) + EPSV);
  __syncthreads();
  float inv = sinv;
  yn[(size_t)m*DI + t]       = f2bf(y0 * inv * rw[t]);
  yn[(size_t)m*DI + t + 256] = f2bf(y1 * inv * rw[t+256]);
}

// ---------- out-proj GEMM (bf16 MFMA), store transposed ----------
__global__ __launch_bounds__(256) void k_gemm_out_mfma(const ushort* __restrict__ ynbf,
                                                       const ushort* __restrict__ wobf,
                                                       float* __restrict__ outp) {
  __shared__ ushort As[128*40];
  __shared__ ushort Bs[64*40];
  const int tid = threadIdx.x;
  const int n0 = blockIdx.x*64, m0 = blockIdx.y*128;
  const int wave = tid>>6, lane = tid&63;
  const int lr = lane&15, quad = lane>>4;
  const int KK = DI;
  f32x4 acc[2][4];
#pragma unroll
  for (int mi=0;mi<2;++mi)
#pragma unroll
    for (int ni=0;ni<4;++ni)
#pragma unroll
      for (int r=0;r<4;++r) acc[mi][ni][r] = 0.f;
  const int srow = tid>>2, sc = tid&3;
  for (int k0 = 0; k0 < KK; k0 += 32) {
    *(uint4*)&As[srow*40 + sc*8]      = *(const uint4*)(ynbf + (size_t)(m0+srow)*KK    + k0 + sc*8);
    *(uint4*)&As[(srow+64)*40 + sc*8] = *(const uint4*)(ynbf + (size_t)(m0+srow+64)*KK + k0 + sc*8);
    *(uint4*)&Bs[srow*40 + sc*8]      = *(const uint4*)(wobf + (size_t)(n0+srow)*KK    + k0 + sc*8);
    __syncthreads();
    bf16x8 af[2], bfr[4];
    const int ar = wave*32 + lr;
    af[0] = *(const bf16x8*)&As[ar*40 + quad*8];
    af[1] = *(const bf16x8*)&As[(ar+16)*40 + quad*8];
#pragma unroll
    for (int ni=0;ni<4;++ni) bfr[ni] = *(const bf16x8*)&Bs[(ni*16+lr)*40 + quad*8];
#pragma unroll
    for (int mi=0;mi<2;++mi)
#pragma unroll
      for (int ni=0;ni<4;++ni)
        acc[mi][ni] = __builtin_amdgcn_mfma_f32_16x16x32_bf16(af[mi], bfr[ni], acc[mi][ni], 0, 0, 0);
    __syncthreads();
  }
  const int b = m0 >> 10, l0 = m0 & 1023;
#pragma unroll
  for (int mi=0;mi<2;++mi) {
    int lb = l0 + wave*32 + mi*16 + quad*4;
#pragma unroll
    for (int ni=0;ni<4;++ni) {
      int n = n0 + ni*16 + lr;
      float4 v = make_float4(acc[mi][ni][0], acc[mi][ni][1], acc[mi][ni][2], acc[mi][ni][3]);
      *(float4*)&outp[(size_t)b*DM*L_ + (size_t)n*L_ + lb] = v;
    }
  }
}

// ---------- GroupNorm + Mish ----------
__global__ __launch_bounds__(256) void k_gn(const float* __restrict__ gw,
                                            const float* __restrict__ gb,
                                            float* __restrict__ o) {
  const int b = blockIdx.x, g = blockIdx.y;
  const int t = threadIdx.x;
  size_t base = (size_t)b*DM*L_ + (size_t)g*32*L_;
  float s = 0.f, ss = 0.f;
  for (int i = t; i < 32*L_; i += 256) {
    float v = o[base+i];
    s += v; ss += v*v;
  }
#pragma unroll
  for (int off = 32; off > 0; off >>= 1) { s += __shfl_down(s, off); ss += __shfl_down(ss, off); }
  __shared__ float rs[4], rss[4];
  __shared__ float smean, sinv;
  if ((t & 63) == 0) { rs[t>>6] = s; rss[t>>6] = ss; }
  __syncthreads();
  if (t == 0) {
    float S = rs[0]+rs[1]+rs[2]+rs[3];
    float SS = rss[0]+rss[1]+rss[2]+rss[3];
    float mean = S * (1.f/(32.f*L_));
    float var  = SS * (1.f/(32.f*L_)) - mean*mean;
    smean = mean; sinv = rsqrtf(var + EPSV);
  }
  __syncthreads();
  float mean = smean, inv = sinv;
  for (int i = t; i < 32*L_; i += 256) {
    int ch = g*32 + (i >> 10);
    float v = (o[base+i] - mean) * inv * gw[ch] + gb[ch];
    float sp = (v > 20.f) ? v : log1pf(expf(v));
    o[base+i] = v * tanhf(sp);
  }
}

extern "C" void kernel_launch(void* const* d_in, const int* in_sizes, int n_in,
                              void* d_out, int out_size, void* d_ws, size_t ws_size,
                              hipStream_t stream) {
  const float* x       = (const float*)d_in[0];
  const float* W_in    = (const float*)d_in[1];
  const float* conv_w  = (const float*)d_in[2];
  const float* conv_b  = (const float*)d_in[3];
  const float* dt_bias = (const float*)d_in[4];
  const float* A_log   = (const float*)d_in[5];
  const float* Dp      = (const float*)d_in[6];
  const float* rms_w   = (const float*)d_in[7];
  const float* W_out   = (const float*)d_in[8];
  const float* gn_w    = (const float*)d_in[9];
  const float* gn_b    = (const float*)d_in[10];
  float* out = (float*)d_out;
  float* ws  = (float*)d_ws;

  float*  zx    = ws + OFF_ZX;
  ushort* xcb   = (ushort*)(ws + OFF_XC);
  float*  dtb   = ws + OFF_DT;
  float*  acs   = ws + OFF_ACS;
  ushort* S0b   = (ushort*)(ws + OFF_S0);
  float*  st    = ws + OFF_ST;
  float*  pv    = ws + OFF_PV;
  float*  Ybuf  = ws + OFF_Y;
  ushort* ynbf  = (ushort*)(ws + OFF_YNB);
  ushort* xbf   = (ushort*)(ws + OFF_XBF);
  ushort* wbf   = (ushort*)(ws + OFF_WBF);
  ushort* wobf  = (ushort*)(ws + OFF_WOBF);

  k_cast_x       <<<dim3(4, 16, 8), 256, 0, stream>>>(x, xbf);
  k_cast         <<<dim3((1296*DM+255)/256), 256, 0, stream>>>(W_in, wbf, 1296*DM);
  k_cast         <<<dim3((DM*DI+255)/256), 256, 0, stream>>>(W_out, wobf, DM*DI);
  k_gemm_in_mfma <<<dim3(NZX/64, M_/128), 256, 0, stream>>>(xbf, wbf, zx);
  k_dt_direct    <<<dim3(M_/16), 256, 0, stream>>>(x, W_in, dt_bias, dtb);
  k_conv         <<<dim3(3, M_), 256, 0, stream>>>(zx, conv_w, conv_b, xcb);
  k_s0_mfma      <<<dim3(4, 4, B_*NC), 256, 0, stream>>>(xcb, S0b);
  k_states       <<<dim3(B_*NC, NH), 256, 0, stream>>>(xcb, dtb, A_log, acs, st);
  k_scan         <<<dim3(B_, NH), 256, 0, stream>>>(acs, st, pv);
  k_y_mfma       <<<dim3(B_*NC, NH), 256, 0, stream>>>(xcb, dtb, acs, S0b, pv, Dp, Ybuf);
  k_rms          <<<dim3(M_), 256, 0, stream>>>(zx, Ybuf, rms_w, ynbf);
  k_gemm_out_mfma<<<dim3(DM/64, M_/128), 256, 0, stream>>>(ynbf, wobf, out);
  k_gn           <<<dim3(B_, 8), 256, 0, stream>>>(gn_w, gn_b, out);
}

// Round 4
// 254.127 us; speedup vs baseline: 2.4222x; 1.3669x over previous
//
#include <hip/hip_runtime.h>
#include <hip/hip_bf16.h>
#include <math.h>

#define B_ 8
#define L_ 1024
#define DM 256
#define DI 512
#define HD 32
#define NH 16
#define DS 128
#define CDIM 768
#define NZX 1280    // z + xBC cols (dt computed separately)
#define CH 256
#define NC 4
#define M_ (B_*L_)
#define EPSV 1e-5f

typedef short bf16x8 __attribute__((ext_vector_type(8)));
typedef float f32x4 __attribute__((ext_vector_type(4)));

// ---- workspace layout (float units) ----
#define OFF_ZX   0                         // M_*NZX fp32
#define SZ_ZX    (M_*NZX)
#define OFF_XC   (OFF_ZX+SZ_ZX)            // M_*CDIM bf16
#define SZ_XC    (M_*CDIM/2)
#define OFF_DT   (OFF_XC+SZ_XC)            // M_*NH fp32
#define SZ_DT    (M_*NH)
#define OFF_ACS  (OFF_DT+SZ_DT)
#define SZ_ACS   (B_*NC*NH*CH)
#define OFF_S0   (OFF_ACS+SZ_ACS)          // bf16 S0b
#define SZ_S0    (B_*NC*CH*CH/2)
#define OFF_ST   (OFF_S0+SZ_S0)
#define SZ_ST    (B_*NC*NH*HD*DS)
#define OFF_PV   (OFF_ST+SZ_ST)
#define SZ_PV    SZ_ST
#define OFF_Y    (OFF_PV+SZ_PV)
#define SZ_Y     (M_*DI)
#define OFF_YNB  (OFF_Y+SZ_Y)              // M_*DI bf16
#define SZ_YNB   (M_*DI/2)
#define OFF_XBF  (OFF_YNB+SZ_YNB)          // M_*DM bf16
#define SZ_XBF   (M_*DM/2)
#define OFF_WBF  (OFF_XBF+SZ_XBF)          // 1296*DM bf16
#define SZ_WBF   (1296*DM/2)
#define OFF_WOBF (OFF_WBF+SZ_WBF)          // DM*DI bf16
#define SZ_WOBF  (DM*DI/2)
#define OFF_GNP  (OFF_WOBF+SZ_WOBF)        // 64*8 float2 partials
#define SZ_GNP   (64*8*2)
#define OFF_GNS  (OFF_GNP+SZ_GNP)          // 64 float2 stats
#define SZ_GNS   (64*2)

__device__ __forceinline__ ushort f2bf(float v) {
  __hip_bfloat16 h = __float2bfloat16(v);
  return *(ushort*)&h;
}
__device__ __forceinline__ float bf2f(ushort u) {
  return __uint_as_float(((unsigned int)u) << 16);
}

// ---------- cast helpers ----------
__global__ void k_cast(const float* __restrict__ s, ushort* __restrict__ d, int n) {
  int i = blockIdx.x*256 + threadIdx.x;
  if (i < n) d[i] = f2bf(s[i]);
}

// transpose+cast x[b][k][l] -> xbf[m=b*L+l][k]
__global__ __launch_bounds__(256) void k_cast_x(const float* __restrict__ x,
                                                ushort* __restrict__ xbf) {
  __shared__ float Ts[64][65];
  const int k0 = blockIdx.x*64, l0 = blockIdx.y*64, b = blockIdx.z;
  const int t = threadIdx.x;
  for (int i = t; i < 4096; i += 256) {
    int kk = i>>6, ll = i&63;
    Ts[kk][ll] = x[(size_t)b*DM*L_ + (size_t)(k0+kk)*L_ + l0+ll];
  }
  __syncthreads();
  for (int i = t; i < 4096; i += 256) {
    int mm = i>>6, kk = i&63;
    xbf[(size_t)(b*L_ + l0+mm)*DM + k0+kk] = f2bf(Ts[kk][mm]);
  }
}

// ---------- in-proj GEMM (bf16 MFMA) ----------
__global__ __launch_bounds__(256) void k_gemm_in_mfma(const ushort* __restrict__ xbf,
                                                      const ushort* __restrict__ wbf,
                                                      float* __restrict__ zx) {
  __shared__ ushort As[128*40];
  __shared__ ushort Bs[64*40];
  const int tid = threadIdx.x;
  const int n0 = blockIdx.x*64, m0 = blockIdx.y*128;
  const int wave = tid>>6, lane = tid&63;
  const int lr = lane&15, quad = lane>>4;
  const int KK = DM;
  f32x4 acc[2][4];
#pragma unroll
  for (int mi=0;mi<2;++mi)
#pragma unroll
    for (int ni=0;ni<4;++ni)
#pragma unroll
      for (int r=0;r<4;++r) acc[mi][ni][r] = 0.f;
  const int srow = tid>>2, sc = tid&3;
  for (int k0 = 0; k0 < KK; k0 += 32) {
    *(uint4*)&As[srow*40 + sc*8]      = *(const uint4*)(xbf + (size_t)(m0+srow)*KK    + k0 + sc*8);
    *(uint4*)&As[(srow+64)*40 + sc*8] = *(const uint4*)(xbf + (size_t)(m0+srow+64)*KK + k0 + sc*8);
    *(uint4*)&Bs[srow*40 + sc*8]      = *(const uint4*)(wbf + (size_t)(n0+srow)*KK    + k0 + sc*8);
    __syncthreads();
    bf16x8 af[2], bfr[4];
    const int ar = wave*32 + lr;
    af[0] = *(const bf16x8*)&As[ar*40 + quad*8];
    af[1] = *(const bf16x8*)&As[(ar+16)*40 + quad*8];
#pragma unroll
    for (int ni=0;ni<4;++ni) bfr[ni] = *(const bf16x8*)&Bs[(ni*16+lr)*40 + quad*8];
#pragma unroll
    for (int mi=0;mi<2;++mi)
#pragma unroll
      for (int ni=0;ni<4;++ni)
        acc[mi][ni] = __builtin_amdgcn_mfma_f32_16x16x32_bf16(af[mi], bfr[ni], acc[mi][ni], 0, 0, 0);
    __syncthreads();
  }
#pragma unroll
  for (int mi=0;mi<2;++mi) {
    int m = m0 + wave*32 + mi*16 + quad*4;
#pragma unroll
    for (int ni=0;ni<4;++ni) {
      int n = n0 + ni*16 + lr;
#pragma unroll
      for (int r=0;r<4;++r) zx[(size_t)(m+r)*NZX + n] = acc[mi][ni][r];
    }
  }
}

// ---------- dt exact fp32 ----------
__global__ __launch_bounds__(256) void k_dt_direct(const float* __restrict__ x,
                                                   const float* __restrict__ W,
                                                   const float* __restrict__ dt_bias,
                                                   float* __restrict__ dtb) {
  __shared__ float Xs[256][16];
  __shared__ float Ws[16][257];
  const int t = threadIdx.x;
  const int bm = blockIdx.x*16;
  const int b = bm >> 10, l0 = bm & 1023;
  for (int i = t; i < 4096; i += 256) {
    int h = i>>8, k = i&255;
    Ws[h][k] = W[(size_t)(NZX+h)*DM + k];
  }
  for (int i = t; i < 4096; i += 256) {
    int k = i>>4, li = i&15;
    Xs[k][li] = x[(size_t)b*DM*L_ + (size_t)k*L_ + l0+li];
  }
  __syncthreads();
  const int h = t&15, li = t>>4;
  float acc = 0.f;
#pragma unroll 8
  for (int k = 0; k < 256; ++k) acc += Xs[k][li]*Ws[h][k];
  float v = acc + dt_bias[h];
  dtb[(size_t)bm*NH + t] = (v > 20.f) ? v : log1pf(expf(v));
}

// ---------- conv4 + SiLU -> bf16 xcb ----------
__global__ void k_conv(const float* __restrict__ zx, const float* __restrict__ cw,
                       const float* __restrict__ cb, ushort* __restrict__ xcb) {
  int j = blockIdx.x*256 + threadIdx.x;
  int m = blockIdx.y;
  if (j >= CDIM) return;
  int l = m & 1023;
  int mb = m - l;
  float acc = cb[j];
#pragma unroll
  for (int k = 0; k < 4; ++k) {
    int ll = l - 3 + k;
    if (ll >= 0) acc += cw[j*4+k] * zx[(size_t)(mb+ll)*NZX + DI + j];
  }
  acc = acc / (1.f + expf(-acc));
  xcb[(size_t)m*CDIM + j] = f2bf(acc);
}

// ---------- S0b = Cm·Bm^T (bf16 MFMA, lower-triangular tiles only) ----------
__global__ __launch_bounds__(256) void k_s0_mfma(const ushort* __restrict__ xcb,
                                                 ushort* __restrict__ S0b) {
  const int lt = blockIdx.x, st = blockIdx.y, bc = blockIdx.z;
  if (st > lt) return;
  const int base = bc*CH;
  const int t = threadIdx.x;
  const int wave = t>>6, lane = t&63, lr = lane&15, quad = lane>>4;
  const int l = lt*64 + wave*16 + lr;
  f32x4 acc[4];
#pragma unroll
  for (int nt = 0; nt < 4; ++nt)
#pragma unroll
    for (int r = 0; r < 4; ++r) acc[nt][r] = 0.f;
#pragma unroll
  for (int ks = 0; ks < 4; ++ks) {
    bf16x8 af = *(const bf16x8*)(xcb + (size_t)(base+l)*CDIM + (DI+DS) + ks*32 + quad*8);
#pragma unroll
    for (int nt = 0; nt < 4; ++nt) {
      bf16x8 bf = *(const bf16x8*)(xcb + (size_t)(base + st*64 + nt*16 + lr)*CDIM + DI + ks*32 + quad*8);
      acc[nt] = __builtin_amdgcn_mfma_f32_16x16x32_bf16(af, bf, acc[nt], 0, 0, 0);
    }
  }
#pragma unroll
  for (int nt = 0; nt < 4; ++nt)
#pragma unroll
    for (int r = 0; r < 4; ++r)
      S0b[((size_t)bc*CH + lt*64 + wave*16 + quad*4 + r)*CH + st*64 + nt*16 + lr] = f2bf(acc[nt][r]);
}

// ---------- per (b,c,h): cumsum(dt*A) + chunk states ----------
__global__ __launch_bounds__(256) void k_states(const ushort* __restrict__ xcb,
                                                const float* __restrict__ dtb,
                                                const float* __restrict__ A_log,
                                                float* __restrict__ acs_g,
                                                float* __restrict__ st) {
  __shared__ float Xs[CH][HD+1];
  __shared__ float acs[CH];
  __shared__ float wv[CH];
  const int t = threadIdx.x;
  const int bc = blockIdx.x, h = blockIdx.y;
  const int base = bc * CH;
  float dt_t = dtb[(size_t)(base+t)*NH + h];
  float An = -expf(A_log[h]);
  acs[t] = dt_t * An;
  for (int i = t; i < CH*HD; i += 256) {
    int l = i >> 5, p = i & 31;
    Xs[l][p] = bf2f(xcb[(size_t)(base+l)*CDIM + h*HD + p]);
  }
  __syncthreads();
  for (int off = 1; off < CH; off <<= 1) {
    float v = (t >= off) ? acs[t-off] : 0.f;
    __syncthreads();
    acs[t] += v;
    __syncthreads();
  }
  float alast = acs[CH-1];
  acs_g[((size_t)bc*NH + h)*CH + t] = acs[t];
  wv[t] = expf(alast - acs[t]) * dt_t;
  __syncthreads();
  const int n = t & 127, ph = t >> 7;
  float acc[16];
#pragma unroll
  for (int i = 0; i < 16; ++i) acc[i] = 0.f;
  for (int l = 0; l < CH; ++l) {
    float bw = bf2f(xcb[(size_t)(base+l)*CDIM + DI + n]) * wv[l];
#pragma unroll
    for (int i = 0; i < 16; ++i) acc[i] += bw * Xs[l][ph*16+i];
  }
  size_t sb = ((size_t)bc*NH + h)*HD*DS;
  for (int i = 0; i < 16; ++i) st[sb + (size_t)(ph*16+i)*DS + n] = acc[i];
}

// ---------- inter-chunk scan ----------
__global__ void k_scan(const float* __restrict__ acs_g, const float* __restrict__ st,
                       float* __restrict__ pv) {
  const int b = blockIdx.x, h = blockIdx.y;
  const int t = threadIdx.x;
  float P[16];
#pragma unroll
  for (int i = 0; i < 16; ++i) P[i] = 0.f;
  for (int c = 0; c < NC; ++c) {
    size_t sb = ((size_t)(b*NC+c)*NH + h)*HD*DS;
    float T = acs_g[((size_t)(b*NC+c)*NH + h)*CH + (CH-1)];
    float ec = expf(T);
#pragma unroll
    for (int i = 0; i < 16; ++i) {
      size_t e = sb + (size_t)i*256 + t;
      pv[e] = P[i];
      P[i] = st[e] + ec * P[i];
    }
  }
}

// ---------- Y = Y_diag + Y_off + D*xs (MFMA) ----------
__global__ __launch_bounds__(256) void k_y_mfma(const ushort* __restrict__ xcb,
    const float* __restrict__ dtb, const float* __restrict__ acs_g,
    const ushort* __restrict__ S0b, const float* __restrict__ pv,
    const float* __restrict__ Dp, float* __restrict__ Y) {
  __shared__ ushort Xt[32][280];
  __shared__ float acs[CH];
  __shared__ float dts[CH];
  __shared__ float E8[CH];
  const int t = threadIdx.x;
  const int bc = blockIdx.x, h = blockIdx.y;
  const int base = bc*CH;
  acs[t] = acs_g[((size_t)bc*NH + h)*CH + t];
  dts[t] = dtb[(size_t)(base+t)*NH + h];
  {
    const ushort* xp = xcb + (size_t)(base+t)*CDIM + h*HD;
    ushort tmp[32];
    *(uint4*)&tmp[0]  = *(const uint4*)(xp);
    *(uint4*)&tmp[8]  = *(const uint4*)(xp+8);
    *(uint4*)&tmp[16] = *(const uint4*)(xp+16);
    *(uint4*)&tmp[24] = *(const uint4*)(xp+24);
#pragma unroll
    for (int p = 0; p < 32; ++p) Xt[p][t] = tmp[p];
  }
  __syncthreads();
  E8[t] = expf(acs[t & ~7] - acs[t]) * dts[t];
  __syncthreads();
  const int wave = t>>6, lane = t&63, lr = lane&15, quad = lane>>4;
  f32x4 acc[4][2];
#pragma unroll
  for (int mt=0;mt<4;++mt)
#pragma unroll
    for (int nt=0;nt<2;++nt)
#pragma unroll
      for (int r=0;r<4;++r) acc[mt][nt][r] = 0.f;
  const size_t pb = ((size_t)bc*NH + h)*HD*DS;
#pragma unroll
  for (int ks = 0; ks < 4; ++ks) {
    bf16x8 bfr[2];
#pragma unroll
    for (int nt = 0; nt < 2; ++nt) {
      const float* pp = pv + pb + (size_t)(nt*16+lr)*DS + ks*32 + quad*8;
      float4 v0 = *(const float4*)pp;
      float4 v1 = *(const float4*)(pp+4);
      bf16x8 bb;
      bb[0]=(short)f2bf(v0.x); bb[1]=(short)f2bf(v0.y); bb[2]=(short)f2bf(v0.z); bb[3]=(short)f2bf(v0.w);
      bb[4]=(short)f2bf(v1.x); bb[5]=(short)f2bf(v1.y); bb[6]=(short)f2bf(v1.z); bb[7]=(short)f2bf(v1.w);
      bfr[nt] = bb;
    }
#pragma unroll
    for (int mt = 0; mt < 4; ++mt) {
      int l = wave*64 + mt*16 + lr;
      bf16x8 af = *(const bf16x8*)(xcb + (size_t)(base+l)*CDIM + (DI+DS) + ks*32 + quad*8);
      acc[mt][0] = __builtin_amdgcn_mfma_f32_16x16x32_bf16(af, bfr[0], acc[mt][0], 0,0,0);
      acc[mt][1] = __builtin_amdgcn_mfma_f32_16x16x32_bf16(af, bfr[1], acc[mt][1], 0,0,0);
    }
  }
#pragma unroll
  for (int mt = 0; mt < 4; ++mt)
#pragma unroll
    for (int r = 0; r < 4; ++r) {
      float e = expf(acs[wave*64 + mt*16 + quad*4 + r]);
      acc[mt][0][r] *= e;
      acc[mt][1][r] *= e;
    }
  float al[4];
#pragma unroll
  for (int mt = 0; mt < 4; ++mt) al[mt] = acs[wave*64 + mt*16 + lr];
  const int km3 = 2*wave + 1;
  for (int ks = 0; ks <= km3; ++ks) {
    const int sq = ks*32 + quad*8;
    const float as0 = acs[sq];
    const float4 e0 = *(const float4*)&E8[sq];
    const float4 e1 = *(const float4*)&E8[sq+4];
    const bf16x8 xb0 = *(const bf16x8*)&Xt[lr][sq];
    const bf16x8 xb1 = *(const bf16x8*)&Xt[16+lr][sq];
    const float ev[8] = {e0.x,e0.y,e0.z,e0.w,e1.x,e1.y,e1.z,e1.w};
#pragma unroll
    for (int mt = 0; mt < 4; ++mt) {
      if (ks > ((wave*64 + mt*16 + 15) >> 5)) continue;
      const int l = wave*64 + mt*16 + lr;
      const bf16x8 sb = *(const bf16x8*)(S0b + ((size_t)bc*CH + l)*CH + sq);
      const float el = expf(al[mt] - as0);
      bf16x8 mf;
#pragma unroll
      for (int j = 0; j < 8; ++j) {
        float v = (sq + j <= l) ? bf2f((ushort)sb[j]) * el * ev[j] : 0.f;
        mf[j] = (short)f2bf(v);
      }
      acc[mt][0] = __builtin_amdgcn_mfma_f32_16x16x32_bf16(mf, xb0, acc[mt][0], 0,0,0);
      acc[mt][1] = __builtin_amdgcn_mfma_f32_16x16x32_bf16(mf, xb1, acc[mt][1], 0,0,0);
    }
  }
  const float dph = Dp[h];
#pragma unroll
  for (int mt = 0; mt < 4; ++mt) {
    const int lb = wave*64 + mt*16 + quad*4;
#pragma unroll
    for (int nt = 0; nt < 2; ++nt) {
      const int p = nt*16 + lr;
#pragma unroll
      for (int r = 0; r < 4; ++r) {
        float xv = bf2f(Xt[p][lb+r]);
        Y[(size_t)(base+lb+r)*DI + h*HD + p] = acc[mt][nt][r] + dph*xv;
      }
    }
  }
}

// ---------- gate + RMSNorm, write bf16 ----------
__global__ __launch_bounds__(256) void k_rms(const float* __restrict__ zx,
                                             const float* __restrict__ Y,
                                             const float* __restrict__ rw,
                                             ushort* __restrict__ yn) {
  const int m = blockIdx.x, t = threadIdx.x;
  float z0 = zx[(size_t)m*NZX + t];
  float z1 = zx[(size_t)m*NZX + t + 256];
  float y0 = Y[(size_t)m*DI + t]       * z0 / (1.f + expf(-z0));
  float y1 = Y[(size_t)m*DI + t + 256] * z1 / (1.f + expf(-z1));
  float ss = y0*y0 + y1*y1;
#pragma unroll
  for (int off = 32; off > 0; off >>= 1) ss += __shfl_down(ss, off);
  __shared__ float red[4];
  __shared__ float sinv;
  if ((t & 63) == 0) red[t >> 6] = ss;
  __syncthreads();
  if (t == 0) sinv = rsqrtf((red[0]+red[1]+red[2]+red[3]) * (1.f/DI) + EPSV);
  __syncthreads();
  float inv = sinv;
  yn[(size_t)m*DI + t]       = f2bf(y0 * inv * rw[t]);
  yn[(size_t)m*DI + t + 256] = f2bf(y1 * inv * rw[t+256]);
}

// ---------- out-proj GEMM (bf16 MFMA), store transposed ----------
__global__ __launch_bounds__(256) void k_gemm_out_mfma(const ushort* __restrict__ ynbf,
                                                       const ushort* __restrict__ wobf,
                                                       float* __restrict__ outp) {
  __shared__ ushort As[128*40];
  __shared__ ushort Bs[64*40];
  const int tid = threadIdx.x;
  const int n0 = blockIdx.x*64, m0 = blockIdx.y*128;
  const int wave = tid>>6, lane = tid&63;
  const int lr = lane&15, quad = lane>>4;
  const int KK = DI;
  f32x4 acc[2][4];
#pragma unroll
  for (int mi=0;mi<2;++mi)
#pragma unroll
    for (int ni=0;ni<4;++ni)
#pragma unroll
      for (int r=0;r<4;++r) acc[mi][ni][r] = 0.f;
  const int srow = tid>>2, sc = tid&3;
  for (int k0 = 0; k0 < KK; k0 += 32) {
    *(uint4*)&As[srow*40 + sc*8]      = *(const uint4*)(ynbf + (size_t)(m0+srow)*KK    + k0 + sc*8);
    *(uint4*)&As[(srow+64)*40 + sc*8] = *(const uint4*)(ynbf + (size_t)(m0+srow+64)*KK + k0 + sc*8);
    *(uint4*)&Bs[srow*40 + sc*8]      = *(const uint4*)(wobf + (size_t)(n0+srow)*KK    + k0 + sc*8);
    __syncthreads();
    bf16x8 af[2], bfr[4];
    const int ar = wave*32 + lr;
    af[0] = *(const bf16x8*)&As[ar*40 + quad*8];
    af[1] = *(const bf16x8*)&As[(ar+16)*40 + quad*8];
#pragma unroll
    for (int ni=0;ni<4;++ni) bfr[ni] = *(const bf16x8*)&Bs[(ni*16+lr)*40 + quad*8];
#pragma unroll
    for (int mi=0;mi<2;++mi)
#pragma unroll
      for (int ni=0;ni<4;++ni)
        acc[mi][ni] = __builtin_amdgcn_mfma_f32_16x16x32_bf16(af[mi], bfr[ni], acc[mi][ni], 0, 0, 0);
    __syncthreads();
  }
  const int b = m0 >> 10, l0 = m0 & 1023;
#pragma unroll
  for (int mi=0;mi<2;++mi) {
    int lb = l0 + wave*32 + mi*16 + quad*4;
#pragma unroll
    for (int ni=0;ni<4;++ni) {
      int n = n0 + ni*16 + lr;
      float4 v = make_float4(acc[mi][ni][0], acc[mi][ni][1], acc[mi][ni][2], acc[mi][ni][3]);
      *(float4*)&outp[(size_t)b*DM*L_ + (size_t)n*L_ + lb] = v;
    }
  }
}

// ---------- GroupNorm: partial sums (64 groups x 8 splits) ----------
__global__ __launch_bounds__(256) void k_gn_part(const float* __restrict__ o,
                                                 float2* __restrict__ part) {
  const int grp = blockIdx.x;       // b*8+g
  const int sp  = blockIdx.y;       // 0..7
  const int t = threadIdx.x;
  size_t base = (size_t)grp*32*L_ + (size_t)sp*4096;
  float s = 0.f, ss = 0.f;
#pragma unroll
  for (int it = 0; it < 4; ++it) {
    float4 v = *(const float4*)&o[base + it*1024 + t*4];
    s  += v.x+v.y+v.z+v.w;
    ss += v.x*v.x+v.y*v.y+v.z*v.z+v.w*v.w;
  }
#pragma unroll
  for (int off = 32; off > 0; off >>= 1) { s += __shfl_down(s, off); ss += __shfl_down(ss, off); }
  __shared__ float rs[4], rss[4];
  if ((t & 63) == 0) { rs[t>>6] = s; rss[t>>6] = ss; }
  __syncthreads();
  if (t == 0) part[grp*8+sp] = make_float2(rs[0]+rs[1]+rs[2]+rs[3], rss[0]+rss[1]+rss[2]+rss[3]);
}

// ---------- GroupNorm: stats ----------
__global__ void k_gn_stats(const float2* __restrict__ part, float2* __restrict__ stats) {
  int g = threadIdx.x;   // 0..63
  float s = 0.f, ss = 0.f;
#pragma unroll
  for (int i = 0; i < 8; ++i) { float2 p = part[g*8+i]; s += p.x; ss += p.y; }
  float mean = s * (1.f/(32.f*L_));
  float var  = ss * (1.f/(32.f*L_)) - mean*mean;
  stats[g] = make_float2(mean, rsqrtf(var + EPSV));
}

// ---------- GroupNorm apply + Mish (one block per (b,ch) row) ----------
__global__ __launch_bounds__(256) void k_gn_apply(const float2* __restrict__ stats,
                                                  const float* __restrict__ gw,
                                                  const float* __restrict__ gb,
                                                  float* __restrict__ o) {
  const int ch = blockIdx.x & 255, b = blockIdx.x >> 8;
  const int t = threadIdx.x;
  float2 st = stats[b*8 + (ch>>5)];
  const float mean = st.x, inv = st.y;
  const float w = gw[ch], bb = gb[ch];
  size_t base = (size_t)blockIdx.x * L_;
  float4 v = *(const float4*)&o[base + t*4];
  float r[4] = {v.x, v.y, v.z, v.w};
#pragma unroll
  for (int j = 0; j < 4; ++j) {
    float u = (r[j] - mean) * inv * w + bb;
    float m;
    if (u > 15.f) m = u;
    else {
      float e = expf(u);
      float a = 1.f + e;
      float a2 = a*a;
      m = u * (a2 - 1.f) / (a2 + 1.f);   // u*tanh(softplus(u)), single exp
    }
    r[j] = m;
  }
  *(float4*)&o[base + t*4] = make_float4(r[0], r[1], r[2], r[3]);
}

extern "C" void kernel_launch(void* const* d_in, const int* in_sizes, int n_in,
                              void* d_out, int out_size, void* d_ws, size_t ws_size,
                              hipStream_t stream) {
  const float* x       = (const float*)d_in[0];
  const float* W_in    = (const float*)d_in[1];
  const float* conv_w  = (const float*)d_in[2];
  const float* conv_b  = (const float*)d_in[3];
  const float* dt_bias = (const float*)d_in[4];
  const float* A_log   = (const float*)d_in[5];
  const float* Dp      = (const float*)d_in[6];
  const float* rms_w   = (const float*)d_in[7];
  const float* W_out   = (const float*)d_in[8];
  const float* gn_w    = (const float*)d_in[9];
  const float* gn_b    = (const float*)d_in[10];
  float* out = (float*)d_out;
  float* ws  = (float*)d_ws;

  float*  zx    = ws + OFF_ZX;
  ushort* xcb   = (ushort*)(ws + OFF_XC);
  float*  dtb   = ws + OFF_DT;
  float*  acs   = ws + OFF_ACS;
  ushort* S0b   = (ushort*)(ws + OFF_S0);
  float*  st    = ws + OFF_ST;
  float*  pv    = ws + OFF_PV;
  float*  Ybuf  = ws + OFF_Y;
  ushort* ynbf  = (ushort*)(ws + OFF_YNB);
  ushort* xbf   = (ushort*)(ws + OFF_XBF);
  ushort* wbf   = (ushort*)(ws + OFF_WBF);
  ushort* wobf  = (ushort*)(ws + OFF_WOBF);
  float2* gnp   = (float2*)(ws + OFF_GNP);
  float2* gns   = (float2*)(ws + OFF_GNS);

  k_cast_x       <<<dim3(4, 16, 8), 256, 0, stream>>>(x, xbf);
  k_cast         <<<dim3((1296*DM+255)/256), 256, 0, stream>>>(W_in, wbf, 1296*DM);
  k_cast         <<<dim3((DM*DI+255)/256), 256, 0, stream>>>(W_out, wobf, DM*DI);
  k_gemm_in_mfma <<<dim3(NZX/64, M_/128), 256, 0, stream>>>(xbf, wbf, zx);
  k_dt_direct    <<<dim3(M_/16), 256, 0, stream>>>(x, W_in, dt_bias, dtb);
  k_conv         <<<dim3(3, M_), 256, 0, stream>>>(zx, conv_w, conv_b, xcb);
  k_s0_mfma      <<<dim3(4, 4, B_*NC), 256, 0, stream>>>(xcb, S0b);
  k_states       <<<dim3(B_*NC, NH), 256, 0, stream>>>(xcb, dtb, A_log, acs, st);
  k_scan         <<<dim3(B_, NH), 256, 0, stream>>>(acs, st, pv);
  k_y_mfma       <<<dim3(B_*NC, NH), 256, 0, stream>>>(xcb, dtb, acs, S0b, pv, Dp, Ybuf);
  k_rms          <<<dim3(M_), 256, 0, stream>>>(zx, Ybuf, rms_w, ynbf);
  k_gemm_out_mfma<<<dim3(DM/64, M_/128), 256, 0, stream>>>(ynbf, wobf, out);
  k_gn_part      <<<dim3(64, 8), 256, 0, stream>>>(out, gnp);
  k_gn_stats     <<<dim3(1), 64, 0, stream>>>(gnp, gns);
  k_gn_apply     <<<dim3(B_*DM), 256, 0, stream>>>(gns, gn_w, gn_b, out);
}

// Round 5
// 205.580 us; speedup vs baseline: 2.9942x; 1.2361x over previous
//
#include <hip/hip_runtime.h>
#include <hip/hip_bf16.h>
#include <math.h>

#define B_ 8
#define L_ 1024
#define DM 256
#define DI 512
#define HD 32
#define NH 16
#define DS 128
#define CDIM 768
#define NZX 1280    // z + xBC cols (dt computed separately)
#define CH 256
#define NC 4
#define M_ (B_*L_)
#define EPSV 1e-5f

typedef short bf16x8 __attribute__((ext_vector_type(8)));
typedef float f32x4 __attribute__((ext_vector_type(4)));

// ---- workspace layout (float units) ----
#define OFF_ZX   0                         // M_*NZX fp32
#define SZ_ZX    (M_*NZX)
#define OFF_XC   (OFF_ZX+SZ_ZX)            // M_*CDIM bf16
#define SZ_XC    (M_*CDIM/2)
#define OFF_DT   (OFF_XC+SZ_XC)            // M_*NH fp32
#define SZ_DT    (M_*NH)
#define OFF_ACS  (OFF_DT+SZ_DT)
#define SZ_ACS   (B_*NC*NH*CH)
#define OFF_S0   (OFF_ACS+SZ_ACS)          // bf16 S0b
#define SZ_S0    (B_*NC*CH*CH/2)
#define OFF_ST   (OFF_S0+SZ_S0)
#define SZ_ST    (B_*NC*NH*HD*DS)
#define OFF_PV   (OFF_ST+SZ_ST)
#define SZ_PV    SZ_ST
#define OFF_Y    (OFF_PV+SZ_PV)
#define SZ_Y     (M_*DI)
#define OFF_YNB  (OFF_Y+SZ_Y)              // M_*DI bf16
#define SZ_YNB   (M_*DI/2)
#define OFF_XBF  (OFF_YNB+SZ_YNB)          // M_*DM bf16
#define SZ_XBF   (M_*DM/2)
#define OFF_WBF  (OFF_XBF+SZ_XBF)          // 1296*DM bf16
#define SZ_WBF   (1296*DM/2)
#define OFF_WOBF (OFF_WBF+SZ_WBF)          // DM*DI bf16
#define SZ_WOBF  (DM*DI/2)
#define OFF_GNP  (OFF_WOBF+SZ_WOBF)        // 64*8 float2 partials
#define SZ_GNP   (64*8*2)
#define OFF_GNS  (OFF_GNP+SZ_GNP)          // 64 float2 stats
#define SZ_GNS   (64*2)
#define OFF_BT   (OFF_GNS+SZ_GNS)          // B^T: 32*128*256 bf16
#define SZ_BT    (32*128*256/2)
#define OFF_XT   (OFF_BT+SZ_BT)            // X^T: 32*512*256 bf16
#define SZ_XT    (32*512*256/2)

__device__ __forceinline__ ushort f2bf(float v) {
  __hip_bfloat16 h = __float2bfloat16(v);
  return *(ushort*)&h;
}
__device__ __forceinline__ float bf2f(ushort u) {
  return __uint_as_float(((unsigned int)u) << 16);
}

// ---------- cast helpers ----------
__global__ void k_cast(const float* __restrict__ s, ushort* __restrict__ d, int n) {
  int i = blockIdx.x*256 + threadIdx.x;
  if (i < n) d[i] = f2bf(s[i]);
}

// transpose+cast x[b][k][l] -> xbf[m=b*L+l][k]
__global__ __launch_bounds__(256) void k_cast_x(const float* __restrict__ x,
                                                ushort* __restrict__ xbf) {
  __shared__ float Ts[64][65];
  const int k0 = blockIdx.x*64, l0 = blockIdx.y*64, b = blockIdx.z;
  const int t = threadIdx.x;
  for (int i = t; i < 4096; i += 256) {
    int kk = i>>6, ll = i&63;
    Ts[kk][ll] = x[(size_t)b*DM*L_ + (size_t)(k0+kk)*L_ + l0+ll];
  }
  __syncthreads();
  for (int i = t; i < 4096; i += 256) {
    int mm = i>>6, kk = i&63;
    xbf[(size_t)(b*L_ + l0+mm)*DM + k0+kk] = f2bf(Ts[kk][mm]);
  }
}

// ---------- generic bf16 column transpose out of xcb: dst[bc][c][l] ----------
__global__ __launch_bounds__(256) void k_xpose(const ushort* __restrict__ xcb,
                                               ushort* __restrict__ dst,
                                               int src_col0, int ncols) {
  __shared__ ushort T[64][66];
  const int c0 = blockIdx.x*64, l0 = blockIdx.y*64, bc = blockIdx.z;
  const int t = threadIdx.x;
  const int base = bc*CH;
  for (int i = t; i < 4096; i += 256) {
    int lr = i>>6, cc = i&63;
    T[lr][cc] = xcb[(size_t)(base+l0+lr)*CDIM + src_col0 + c0+cc];
  }
  __syncthreads();
  for (int i = t; i < 4096; i += 256) {
    int cc = i>>6, lr = i&63;
    dst[((size_t)bc*ncols + c0+cc)*CH + l0+lr] = T[lr][cc];
  }
}

// ---------- in-proj GEMM (bf16 MFMA) ----------
__global__ __launch_bounds__(256) void k_gemm_in_mfma(const ushort* __restrict__ xbf,
                                                      const ushort* __restrict__ wbf,
                                                      float* __restrict__ zx) {
  __shared__ ushort As[128*40];
  __shared__ ushort Bs[64*40];
  const int tid = threadIdx.x;
  const int n0 = blockIdx.x*64, m0 = blockIdx.y*128;
  const int wave = tid>>6, lane = tid&63;
  const int lr = lane&15, quad = lane>>4;
  const int KK = DM;
  f32x4 acc[2][4];
#pragma unroll
  for (int mi=0;mi<2;++mi)
#pragma unroll
    for (int ni=0;ni<4;++ni)
#pragma unroll
      for (int r=0;r<4;++r) acc[mi][ni][r] = 0.f;
  const int srow = tid>>2, sc = tid&3;
  for (int k0 = 0; k0 < KK; k0 += 32) {
    *(uint4*)&As[srow*40 + sc*8]      = *(const uint4*)(xbf + (size_t)(m0+srow)*KK    + k0 + sc*8);
    *(uint4*)&As[(srow+64)*40 + sc*8] = *(const uint4*)(xbf + (size_t)(m0+srow+64)*KK + k0 + sc*8);
    *(uint4*)&Bs[srow*40 + sc*8]      = *(const uint4*)(wbf + (size_t)(n0+srow)*KK    + k0 + sc*8);
    __syncthreads();
    bf16x8 af[2], bfr[4];
    const int ar = wave*32 + lr;
    af[0] = *(const bf16x8*)&As[ar*40 + quad*8];
    af[1] = *(const bf16x8*)&As[(ar+16)*40 + quad*8];
#pragma unroll
    for (int ni=0;ni<4;++ni) bfr[ni] = *(const bf16x8*)&Bs[(ni*16+lr)*40 + quad*8];
#pragma unroll
    for (int mi=0;mi<2;++mi)
#pragma unroll
      for (int ni=0;ni<4;++ni)
        acc[mi][ni] = __builtin_amdgcn_mfma_f32_16x16x32_bf16(af[mi], bfr[ni], acc[mi][ni], 0, 0, 0);
    __syncthreads();
  }
#pragma unroll
  for (int mi=0;mi<2;++mi) {
    int m = m0 + wave*32 + mi*16 + quad*4;
#pragma unroll
    for (int ni=0;ni<4;++ni) {
      int n = n0 + ni*16 + lr;
#pragma unroll
      for (int r=0;r<4;++r) zx[(size_t)(m+r)*NZX + n] = acc[mi][ni][r];
    }
  }
}

// ---------- dt exact fp32 ----------
__global__ __launch_bounds__(256) void k_dt_direct(const float* __restrict__ x,
                                                   const float* __restrict__ W,
                                                   const float* __restrict__ dt_bias,
                                                   float* __restrict__ dtb) {
  __shared__ float Xs[256][16];
  __shared__ float Ws[16][257];
  const int t = threadIdx.x;
  const int bm = blockIdx.x*16;
  const int b = bm >> 10, l0 = bm & 1023;
  for (int i = t; i < 4096; i += 256) {
    int h = i>>8, k = i&255;
    Ws[h][k] = W[(size_t)(NZX+h)*DM + k];
  }
  for (int i = t; i < 4096; i += 256) {
    int k = i>>4, li = i&15;
    Xs[k][li] = x[(size_t)b*DM*L_ + (size_t)k*L_ + l0+li];
  }
  __syncthreads();
  const int h = t&15, li = t>>4;
  float acc = 0.f;
#pragma unroll 8
  for (int k = 0; k < 256; ++k) acc += Xs[k][li]*Ws[h][k];
  float v = acc + dt_bias[h];
  dtb[(size_t)bm*NH + t] = (v > 20.f) ? v : log1pf(expf(v));
}

// ---------- conv4 + SiLU -> bf16 xcb (4 outputs per thread, reuse loads) ----------
__global__ __launch_bounds__(256) void k_conv(const float* __restrict__ zx,
                                              const float* __restrict__ cw,
                                              const float* __restrict__ cb,
                                              ushort* __restrict__ xcb) {
  const int j = blockIdx.x*256 + threadIdx.x;          // 0..767
  const int l0 = (blockIdx.y*4) & 1023;
  const int mb = (blockIdx.y*4) & ~1023;               // b*1024
  const float4 w = *(const float4*)&cw[j*4];
  const float bias = cb[j];
  float v[7];
#pragma unroll
  for (int i = 0; i < 7; ++i) {
    int ll = l0 - 3 + i;
    v[i] = (ll >= 0) ? zx[(size_t)(mb+ll)*NZX + DI + j] : 0.f;
  }
#pragma unroll
  for (int i = 0; i < 4; ++i) {
    float a = bias + w.x*v[i] + w.y*v[i+1] + w.z*v[i+2] + w.w*v[i+3];
    a = a / (1.f + expf(-a));
    xcb[(size_t)(mb+l0+i)*CDIM + j] = f2bf(a);
  }
}

// ---------- S0b = Cm·Bm^T (bf16 MFMA, lower-triangular tiles only) ----------
__global__ __launch_bounds__(256) void k_s0_mfma(const ushort* __restrict__ xcb,
                                                 ushort* __restrict__ S0b) {
  const int lt = blockIdx.x, st = blockIdx.y, bc = blockIdx.z;
  if (st > lt) return;
  const int base = bc*CH;
  const int t = threadIdx.x;
  const int wave = t>>6, lane = t&63, lr = lane&15, quad = lane>>4;
  const int l = lt*64 + wave*16 + lr;
  f32x4 acc[4];
#pragma unroll
  for (int nt = 0; nt < 4; ++nt)
#pragma unroll
    for (int r = 0; r < 4; ++r) acc[nt][r] = 0.f;
#pragma unroll
  for (int ks = 0; ks < 4; ++ks) {
    bf16x8 af = *(const bf16x8*)(xcb + (size_t)(base+l)*CDIM + (DI+DS) + ks*32 + quad*8);
#pragma unroll
    for (int nt = 0; nt < 4; ++nt) {
      bf16x8 bf = *(const bf16x8*)(xcb + (size_t)(base + st*64 + nt*16 + lr)*CDIM + DI + ks*32 + quad*8);
      acc[nt] = __builtin_amdgcn_mfma_f32_16x16x32_bf16(af, bf, acc[nt], 0, 0, 0);
    }
  }
#pragma unroll
  for (int nt = 0; nt < 4; ++nt)
#pragma unroll
    for (int r = 0; r < 4; ++r)
      S0b[((size_t)bc*CH + lt*64 + wave*16 + quad*4 + r)*CH + st*64 + nt*16 + lr] = f2bf(acc[nt][r]);
}

// ---------- per (b,c,h): cumsum + chunk states via MFMA ----------
// st[p][n] = sum_l (X[l][p]*wv[l]) * B[l][n];  A = Xw^T (LDS), B = B^T (global)
__global__ __launch_bounds__(256) void k_states_mfma(const ushort* __restrict__ xtg,
                                                     const ushort* __restrict__ btg,
                                                     const float* __restrict__ dtb,
                                                     const float* __restrict__ A_log,
                                                     float* __restrict__ acs_g,
                                                     float* __restrict__ st) {
  __shared__ float acs[CH];
  __shared__ float wv[CH];
  __shared__ ushort Xw[32][264];
  const int t = threadIdx.x;
  const int bc = blockIdx.x, h = blockIdx.y;
  const int base = bc*CH;
  float dt_t = dtb[(size_t)(base+t)*NH + h];
  float An = -expf(A_log[h]);
  acs[t] = dt_t * An;
  __syncthreads();
  for (int off = 1; off < CH; off <<= 1) {
    float v = (t >= off) ? acs[t-off] : 0.f;
    __syncthreads();
    acs[t] += v;
    __syncthreads();
  }
  float alast = acs[CH-1];
  acs_g[((size_t)bc*NH + h)*CH + t] = acs[t];
  wv[t] = expf(alast - acs[t]) * dt_t;
  __syncthreads();
  // stage Xw[p][l] = XT[h*32+p][l] * wv[l]  (b128 in, b128 out, no transpose)
  {
    const int p = t>>3, lc = (t&7)*32;
    const ushort* xp = xtg + ((size_t)bc*DI + h*HD + p)*CH + lc;
#pragma unroll
    for (int c = 0; c < 4; ++c) {
      bf16x8 xv = *(const bf16x8*)(xp + c*8);
      bf16x8 o;
#pragma unroll
      for (int j = 0; j < 8; ++j)
        o[j] = (short)f2bf(bf2f((ushort)xv[j]) * wv[lc + c*8 + j]);
      *(bf16x8*)&Xw[p][lc + c*8] = o;
    }
  }
  __syncthreads();
  const int wave = t>>6, lane = t&63, lr = lane&15, quad = lane>>4;
  f32x4 acc[2][2];
#pragma unroll
  for (int mt=0;mt<2;++mt)
#pragma unroll
    for (int nt=0;nt<2;++nt)
#pragma unroll
      for (int r=0;r<4;++r) acc[mt][nt][r] = 0.f;
  const ushort* bp = btg + (size_t)bc*DS*CH;
#pragma unroll
  for (int k0 = 0; k0 < CH; k0 += 32) {
    bf16x8 a0 = *(const bf16x8*)&Xw[lr][k0 + quad*8];
    bf16x8 a1 = *(const bf16x8*)&Xw[16+lr][k0 + quad*8];
    bf16x8 b0 = *(const bf16x8*)(bp + (size_t)(wave*32 + lr)*CH + k0 + quad*8);
    bf16x8 b1 = *(const bf16x8*)(bp + (size_t)(wave*32 + 16 + lr)*CH + k0 + quad*8);
    acc[0][0] = __builtin_amdgcn_mfma_f32_16x16x32_bf16(a0, b0, acc[0][0], 0,0,0);
    acc[0][1] = __builtin_amdgcn_mfma_f32_16x16x32_bf16(a0, b1, acc[0][1], 0,0,0);
    acc[1][0] = __builtin_amdgcn_mfma_f32_16x16x32_bf16(a1, b0, acc[1][0], 0,0,0);
    acc[1][1] = __builtin_amdgcn_mfma_f32_16x16x32_bf16(a1, b1, acc[1][1], 0,0,0);
  }
  size_t sb = ((size_t)bc*NH + h)*HD*DS;
#pragma unroll
  for (int mt = 0; mt < 2; ++mt)
#pragma unroll
    for (int nt = 0; nt < 2; ++nt)
#pragma unroll
      for (int r = 0; r < 4; ++r)
        st[sb + (size_t)(mt*16 + quad*4 + r)*DS + wave*32 + nt*16 + lr] = acc[mt][nt][r];
}

// ---------- inter-chunk scan ----------
__global__ void k_scan(const float* __restrict__ acs_g, const float* __restrict__ st,
                       float* __restrict__ pv) {
  const int b = blockIdx.x, h = blockIdx.y;
  const int t = threadIdx.x;
  float P[16];
#pragma unroll
  for (int i = 0; i < 16; ++i) P[i] = 0.f;
  for (int c = 0; c < NC; ++c) {
    size_t sb = ((size_t)(b*NC+c)*NH + h)*HD*DS;
    float T = acs_g[((size_t)(b*NC+c)*NH + h)*CH + (CH-1)];
    float ec = expf(T);
#pragma unroll
    for (int i = 0; i < 16; ++i) {
      size_t e = sb + (size_t)i*256 + t;
      pv[e] = P[i];
      P[i] = st[e] + ec * P[i];
    }
  }
}

// ---------- Y = Y_diag + Y_off + D*xs (MFMA) ----------
__global__ __launch_bounds__(256) void k_y_mfma(const ushort* __restrict__ xcb,
    const float* __restrict__ dtb, const float* __restrict__ acs_g,
    const ushort* __restrict__ S0b, const float* __restrict__ pv,
    const float* __restrict__ Dp, float* __restrict__ Y) {
  __shared__ ushort Xt[32][280];
  __shared__ float acs[CH];
  __shared__ float dts[CH];
  __shared__ float E8[CH];
  const int t = threadIdx.x;
  const int bc = blockIdx.x, h = blockIdx.y;
  const int base = bc*CH;
  acs[t] = acs_g[((size_t)bc*NH + h)*CH + t];
  dts[t] = dtb[(size_t)(base+t)*NH + h];
  {
    const ushort* xp = xcb + (size_t)(base+t)*CDIM + h*HD;
    ushort tmp[32];
    *(uint4*)&tmp[0]  = *(const uint4*)(xp);
    *(uint4*)&tmp[8]  = *(const uint4*)(xp+8);
    *(uint4*)&tmp[16] = *(const uint4*)(xp+16);
    *(uint4*)&tmp[24] = *(const uint4*)(xp+24);
#pragma unroll
    for (int p = 0; p < 32; ++p) Xt[p][t] = tmp[p];
  }
  __syncthreads();
  E8[t] = expf(acs[t & ~7] - acs[t]) * dts[t];
  __syncthreads();
  const int wave = t>>6, lane = t&63, lr = lane&15, quad = lane>>4;
  f32x4 acc[4][2];
#pragma unroll
  for (int mt=0;mt<4;++mt)
#pragma unroll
    for (int nt=0;nt<2;++nt)
#pragma unroll
      for (int r=0;r<4;++r) acc[mt][nt][r] = 0.f;
  const size_t pb = ((size_t)bc*NH + h)*HD*DS;
#pragma unroll
  for (int ks = 0; ks < 4; ++ks) {
    bf16x8 bfr[2];
#pragma unroll
    for (int nt = 0; nt < 2; ++nt) {
      const float* pp = pv + pb + (size_t)(nt*16+lr)*DS + ks*32 + quad*8;
      float4 v0 = *(const float4*)pp;
      float4 v1 = *(const float4*)(pp+4);
      bf16x8 bb;
      bb[0]=(short)f2bf(v0.x); bb[1]=(short)f2bf(v0.y); bb[2]=(short)f2bf(v0.z); bb[3]=(short)f2bf(v0.w);
      bb[4]=(short)f2bf(v1.x); bb[5]=(short)f2bf(v1.y); bb[6]=(short)f2bf(v1.z); bb[7]=(short)f2bf(v1.w);
      bfr[nt] = bb;
    }
#pragma unroll
    for (int mt = 0; mt < 4; ++mt) {
      int l = wave*64 + mt*16 + lr;
      bf16x8 af = *(const bf16x8*)(xcb + (size_t)(base+l)*CDIM + (DI+DS) + ks*32 + quad*8);
      acc[mt][0] = __builtin_amdgcn_mfma_f32_16x16x32_bf16(af, bfr[0], acc[mt][0], 0,0,0);
      acc[mt][1] = __builtin_amdgcn_mfma_f32_16x16x32_bf16(af, bfr[1], acc[mt][1], 0,0,0);
    }
  }
#pragma unroll
  for (int mt = 0; mt < 4; ++mt)
#pragma unroll
    for (int r = 0; r < 4; ++r) {
      float e = expf(acs[wave*64 + mt*16 + quad*4 + r]);
      acc[mt][0][r] *= e;
      acc[mt][1][r] *= e;
    }
  float al[4];
#pragma unroll
  for (int mt = 0; mt < 4; ++mt) al[mt] = acs[wave*64 + mt*16 + lr];
  const int km3 = 2*wave + 1;
  for (int ks = 0; ks <= km3; ++ks) {
    const int sq = ks*32 + quad*8;
    const float as0 = acs[sq];
    const float4 e0 = *(const float4*)&E8[sq];
    const float4 e1 = *(const float4*)&E8[sq+4];
    const bf16x8 xb0 = *(const bf16x8*)&Xt[lr][sq];
    const bf16x8 xb1 = *(const bf16x8*)&Xt[16+lr][sq];
    const float ev[8] = {e0.x,e0.y,e0.z,e0.w,e1.x,e1.y,e1.z,e1.w};
#pragma unroll
    for (int mt = 0; mt < 4; ++mt) {
      if (ks > ((wave*64 + mt*16 + 15) >> 5)) continue;
      const int l = wave*64 + mt*16 + lr;
      const bf16x8 sb = *(const bf16x8*)(S0b + ((size_t)bc*CH + l)*CH + sq);
      const float el = expf(al[mt] - as0);
      bf16x8 mf;
#pragma unroll
      for (int j = 0; j < 8; ++j) {
        float v = (sq + j <= l) ? bf2f((ushort)sb[j]) * el * ev[j] : 0.f;
        mf[j] = (short)f2bf(v);
      }
      acc[mt][0] = __builtin_amdgcn_mfma_f32_16x16x32_bf16(mf, xb0, acc[mt][0], 0,0,0);
      acc[mt][1] = __builtin_amdgcn_mfma_f32_16x16x32_bf16(mf, xb1, acc[mt][1], 0,0,0);
    }
  }
  const float dph = Dp[h];
#pragma unroll
  for (int mt = 0; mt < 4; ++mt) {
    const int lb = wave*64 + mt*16 + quad*4;
#pragma unroll
    for (int nt = 0; nt < 2; ++nt) {
      const int p = nt*16 + lr;
#pragma unroll
      for (int r = 0; r < 4; ++r) {
        float xv = bf2f(Xt[p][lb+r]);
        Y[(size_t)(base+lb+r)*DI + h*HD + p] = acc[mt][nt][r] + dph*xv;
      }
    }
  }
}

// ---------- gate + RMSNorm, write bf16 ----------
__global__ __launch_bounds__(256) void k_rms(const float* __restrict__ zx,
                                             const float* __restrict__ Y,
                                             const float* __restrict__ rw,
                                             ushort* __restrict__ yn) {
  const int m = blockIdx.x, t = threadIdx.x;
  float z0 = zx[(size_t)m*NZX + t];
  float z1 = zx[(size_t)m*NZX + t + 256];
  float y0 = Y[(size_t)m*DI + t]       * z0 / (1.f + expf(-z0));
  float y1 = Y[(size_t)m*DI + t + 256] * z1 / (1.f + expf(-z1));
  float ss = y0*y0 + y1*y1;
#pragma unroll
  for (int off = 32; off > 0; off >>= 1) ss += __shfl_down(ss, off);
  __shared__ float red[4];
  __shared__ float sinv;
  if ((t & 63) == 0) red[t >> 6] = ss;
  __syncthreads();
  if (t == 0) sinv = rsqrtf((red[0]+red[1]+red[2]+red[3]) * (1.f/DI) + EPSV);
  __syncthreads();
  float inv = sinv;
  yn[(size_t)m*DI + t]       = f2bf(y0 * inv * rw[t]);
  yn[(size_t)m*DI + t + 256] = f2bf(y1 * inv * rw[t+256]);
}

// ---------- out-proj GEMM (bf16 MFMA), store transposed ----------
__global__ __launch_bounds__(256) void k_gemm_out_mfma(const ushort* __restrict__ ynbf,
                                                       const ushort* __restrict__ wobf,
                                                       float* __restrict__ outp) {
  __shared__ ushort As[128*40];
  __shared__ ushort Bs[64*40];
  const int tid = threadIdx.x;
  const int n0 = blockIdx.x*64, m0 = blockIdx.y*128;
  const int wave = tid>>6, lane = tid&63;
  const int lr = lane&15, quad = lane>>4;
  const int KK = DI;
  f32x4 acc[2][4];
#pragma unroll
  for (int mi=0;mi<2;++mi)
#pragma unroll
    for (int ni=0;ni<4;++ni)
#pragma unroll
      for (int r=0;r<4;++r) acc[mi][ni][r] = 0.f;
  const int srow = tid>>2, sc = tid&3;
  for (int k0 = 0; k0 < KK; k0 += 32) {
    *(uint4*)&As[srow*40 + sc*8]      = *(const uint4*)(ynbf + (size_t)(m0+srow)*KK    + k0 + sc*8);
    *(uint4*)&As[(srow+64)*40 + sc*8] = *(const uint4*)(ynbf + (size_t)(m0+srow+64)*KK + k0 + sc*8);
    *(uint4*)&Bs[srow*40 + sc*8]      = *(const uint4*)(wobf + (size_t)(n0+srow)*KK    + k0 + sc*8);
    __syncthreads();
    bf16x8 af[2], bfr[4];
    const int ar = wave*32 + lr;
    af[0] = *(const bf16x8*)&As[ar*40 + quad*8];
    af[1] = *(const bf16x8*)&As[(ar+16)*40 + quad*8];
#pragma unroll
    for (int ni=0;ni<4;++ni) bfr[ni] = *(const bf16x8*)&Bs[(ni*16+lr)*40 + quad*8];
#pragma unroll
    for (int mi=0;mi<2;++mi)
#pragma unroll
      for (int ni=0;ni<4;++ni)
        acc[mi][ni] = __builtin_amdgcn_mfma_f32_16x16x32_bf16(af[mi], bfr[ni], acc[mi][ni], 0, 0, 0);
    __syncthreads();
  }
  const int b = m0 >> 10, l0 = m0 & 1023;
#pragma unroll
  for (int mi=0;mi<2;++mi) {
    int lb = l0 + wave*32 + mi*16 + quad*4;
#pragma unroll
    for (int ni=0;ni<4;++ni) {
      int n = n0 + ni*16 + lr;
      float4 v = make_float4(acc[mi][ni][0], acc[mi][ni][1], acc[mi][ni][2], acc[mi][ni][3]);
      *(float4*)&outp[(size_t)b*DM*L_ + (size_t)n*L_ + lb] = v;
    }
  }
}

// ---------- GroupNorm: partial sums ----------
__global__ __launch_bounds__(256) void k_gn_part(const float* __restrict__ o,
                                                 float2* __restrict__ part) {
  const int grp = blockIdx.x;
  const int sp  = blockIdx.y;
  const int t = threadIdx.x;
  size_t base = (size_t)grp*32*L_ + (size_t)sp*4096;
  float s = 0.f, ss = 0.f;
#pragma unroll
  for (int it = 0; it < 4; ++it) {
    float4 v = *(const float4*)&o[base + it*1024 + t*4];
    s  += v.x+v.y+v.z+v.w;
    ss += v.x*v.x+v.y*v.y+v.z*v.z+v.w*v.w;
  }
#pragma unroll
  for (int off = 32; off > 0; off >>= 1) { s += __shfl_down(s, off); ss += __shfl_down(ss, off); }
  __shared__ float rs[4], rss[4];
  if ((t & 63) == 0) { rs[t>>6] = s; rss[t>>6] = ss; }
  __syncthreads();
  if (t == 0) part[grp*8+sp] = make_float2(rs[0]+rs[1]+rs[2]+rs[3], rss[0]+rss[1]+rss[2]+rss[3]);
}

// ---------- GroupNorm: stats ----------
__global__ void k_gn_stats(const float2* __restrict__ part, float2* __restrict__ stats) {
  int g = threadIdx.x;
  float s = 0.f, ss = 0.f;
#pragma unroll
  for (int i = 0; i < 8; ++i) { float2 p = part[g*8+i]; s += p.x; ss += p.y; }
  float mean = s * (1.f/(32.f*L_));
  float var  = ss * (1.f/(32.f*L_)) - mean*mean;
  stats[g] = make_float2(mean, rsqrtf(var + EPSV));
}

// ---------- GroupNorm apply + Mish ----------
__global__ __launch_bounds__(256) void k_gn_apply(const float2* __restrict__ stats,
                                                  const float* __restrict__ gw,
                                                  const float* __restrict__ gb,
                                                  float* __restrict__ o) {
  const int ch = blockIdx.x & 255, b = blockIdx.x >> 8;
  const int t = threadIdx.x;
  float2 st = stats[b*8 + (ch>>5)];
  const float mean = st.x, inv = st.y;
  const float w = gw[ch], bb = gb[ch];
  size_t base = (size_t)blockIdx.x * L_;
  float4 v = *(const float4*)&o[base + t*4];
  float r[4] = {v.x, v.y, v.z, v.w};
#pragma unroll
  for (int j = 0; j < 4; ++j) {
    float u = (r[j] - mean) * inv * w + bb;
    float m;
    if (u > 15.f) m = u;
    else {
      float e = expf(u);
      float a = 1.f + e;
      float a2 = a*a;
      m = u * (a2 - 1.f) / (a2 + 1.f);
    }
    r[j] = m;
  }
  *(float4*)&o[base + t*4] = make_float4(r[0], r[1], r[2], r[3]);
}

extern "C" void kernel_launch(void* const* d_in, const int* in_sizes, int n_in,
                              void* d_out, int out_size, void* d_ws, size_t ws_size,
                              hipStream_t stream) {
  const float* x       = (const float*)d_in[0];
  const float* W_in    = (const float*)d_in[1];
  const float* conv_w  = (const float*)d_in[2];
  const float* conv_b  = (const float*)d_in[3];
  const float* dt_bias = (const float*)d_in[4];
  const float* A_log   = (const float*)d_in[5];
  const float* Dp      = (const float*)d_in[6];
  const float* rms_w   = (const float*)d_in[7];
  const float* W_out   = (const float*)d_in[8];
  const float* gn_w    = (const float*)d_in[9];
  const float* gn_b    = (const float*)d_in[10];
  float* out = (float*)d_out;
  float* ws  = (float*)d_ws;

  float*  zx    = ws + OFF_ZX;
  ushort* xcb   = (ushort*)(ws + OFF_XC);
  float*  dtb   = ws + OFF_DT;
  float*  acs   = ws + OFF_ACS;
  ushort* S0b   = (ushort*)(ws + OFF_S0);
  float*  st    = ws + OFF_ST;
  float*  pv    = ws + OFF_PV;
  float*  Ybuf  = ws + OFF_Y;
  ushort* ynbf  = (ushort*)(ws + OFF_YNB);
  ushort* xbf   = (ushort*)(ws + OFF_XBF);
  ushort* wbf   = (ushort*)(ws + OFF_WBF);
  ushort* wobf  = (ushort*)(ws + OFF_WOBF);
  float2* gnp   = (float2*)(ws + OFF_GNP);
  float2* gns   = (float2*)(ws + OFF_GNS);
  ushort* btg   = (ushort*)(ws + OFF_BT);
  ushort* xtg   = (ushort*)(ws + OFF_XT);

  k_cast_x       <<<dim3(4, 16, 8), 256, 0, stream>>>(x, xbf);
  k_cast         <<<dim3((1296*DM+255)/256), 256, 0, stream>>>(W_in, wbf, 1296*DM);
  k_cast         <<<dim3((DM*DI+255)/256), 256, 0, stream>>>(W_out, wobf, DM*DI);
  k_gemm_in_mfma <<<dim3(NZX/64, M_/128), 256, 0, stream>>>(xbf, wbf, zx);
  k_dt_direct    <<<dim3(M_/16), 256, 0, stream>>>(x, W_in, dt_bias, dtb);
  k_conv         <<<dim3(3, M_/4), 256, 0, stream>>>(zx, conv_w, conv_b, xcb);
  k_xpose        <<<dim3(2, 4, B_*NC), 256, 0, stream>>>(xcb, btg, DI, DS);
  k_xpose        <<<dim3(8, 4, B_*NC), 256, 0, stream>>>(xcb, xtg, 0, DI);
  k_s0_mfma      <<<dim3(4, 4, B_*NC), 256, 0, stream>>>(xcb, S0b);
  k_states_mfma  <<<dim3(B_*NC, NH), 256, 0, stream>>>(xtg, btg, dtb, A_log, acs, st);
  k_scan         <<<dim3(B_, NH), 256, 0, stream>>>(acs, st, pv);
  k_y_mfma       <<<dim3(B_*NC, NH), 256, 0, stream>>>(xcb, dtb, acs, S0b, pv, Dp, Ybuf);
  k_rms          <<<dim3(M_), 256, 0, stream>>>(zx, Ybuf, rms_w, ynbf);
  k_gemm_out_mfma<<<dim3(DM/64, M_/128), 256, 0, stream>>>(ynbf, wobf, out);
  k_gn_part      <<<dim3(64, 8), 256, 0, stream>>>(out, gnp);
  k_gn_stats     <<<dim3(1), 64, 0, stream>>>(gnp, gns);
  k_gn_apply     <<<dim3(B_*DM), 256, 0, stream>>>(gns, gn_w, gn_b, out);
}

// Round 6
// 197.394 us; speedup vs baseline: 3.1183x; 1.0415x over previous
//
#include <hip/hip_runtime.h>
#include <hip/hip_bf16.h>
#include <math.h>

#define B_ 8
#define L_ 1024
#define DM 256
#define DI 512
#define HD 32
#define NH 16
#define DS 128
#define CDIM 768
#define NZX 1280    // z + xBC cols (dt computed separately)
#define CH 256
#define NC 4
#define M_ (B_*L_)
#define EPSV 1e-5f

typedef short bf16x8 __attribute__((ext_vector_type(8)));
typedef float f32x4 __attribute__((ext_vector_type(4)));

// ---- workspace layout (float units) ----
#define OFF_ZX   0                         // M_*NZX bf16
#define SZ_ZX    (M_*NZX/2)
#define OFF_XC   (OFF_ZX+SZ_ZX)            // M_*CDIM bf16
#define SZ_XC    (M_*CDIM/2)
#define OFF_DT   (OFF_XC+SZ_XC)            // M_*NH fp32
#define SZ_DT    (M_*NH)
#define OFF_ACS  (OFF_DT+SZ_DT)
#define SZ_ACS   (B_*NC*NH*CH)
#define OFF_S0   (OFF_ACS+SZ_ACS)          // bf16 S0b
#define SZ_S0    (B_*NC*CH*CH/2)
#define OFF_ST   (OFF_S0+SZ_S0)
#define SZ_ST    (B_*NC*NH*HD*DS)
#define OFF_PV   (OFF_ST+SZ_ST)
#define SZ_PV    SZ_ST
#define OFF_Y    (OFF_PV+SZ_PV)            // M_*DI bf16
#define SZ_Y     (M_*DI/2)
#define OFF_YNB  (OFF_Y+SZ_Y)              // M_*DI bf16
#define SZ_YNB   (M_*DI/2)
#define OFF_XBF  (OFF_YNB+SZ_YNB)          // M_*DM bf16
#define SZ_XBF   (M_*DM/2)
#define OFF_WBF  (OFF_XBF+SZ_XBF)          // 1296*DM bf16
#define SZ_WBF   (1296*DM/2)
#define OFF_WOBF (OFF_WBF+SZ_WBF)          // DM*DI bf16
#define SZ_WOBF  (DM*DI/2)
#define OFF_GNP  (OFF_WOBF+SZ_WOBF)        // 64 float2 group accumulators
#define SZ_GNP   (64*2)
#define OFF_BT   (OFF_GNP+SZ_GNP)          // B^T: 32*128*256 bf16
#define SZ_BT    (32*128*256/2)

__device__ __forceinline__ ushort f2bf(float v) {
  __hip_bfloat16 h = __float2bfloat16(v);
  return *(ushort*)&h;
}
__device__ __forceinline__ float bf2f(ushort u) {
  return __uint_as_float(((unsigned int)u) << 16);
}

// ---------- zero the GN accumulators ----------
__global__ void k_zero_gnp(float2* __restrict__ gnp) {
  gnp[threadIdx.x] = make_float2(0.f, 0.f);
}

// ---------- cast helpers ----------
__global__ void k_cast(const float* __restrict__ s, ushort* __restrict__ d, int n) {
  int i = blockIdx.x*256 + threadIdx.x;
  if (i < n) d[i] = f2bf(s[i]);
}

// transpose+cast x[b][k][l] -> xbf[m=b*L+l][k]
__global__ __launch_bounds__(256) void k_cast_x(const float* __restrict__ x,
                                                ushort* __restrict__ xbf) {
  __shared__ float Ts[64][65];
  const int k0 = blockIdx.x*64, l0 = blockIdx.y*64, b = blockIdx.z;
  const int t = threadIdx.x;
  for (int i = t; i < 4096; i += 256) {
    int kk = i>>6, ll = i&63;
    Ts[kk][ll] = x[(size_t)b*DM*L_ + (size_t)(k0+kk)*L_ + l0+ll];
  }
  __syncthreads();
  for (int i = t; i < 4096; i += 256) {
    int mm = i>>6, kk = i&63;
    xbf[(size_t)(b*L_ + l0+mm)*DM + k0+kk] = f2bf(Ts[kk][mm]);
  }
}

// ---------- bf16 column transpose out of xcb: dst[bc][c][l] ----------
__global__ __launch_bounds__(256) void k_xpose(const ushort* __restrict__ xcb,
                                               ushort* __restrict__ dst,
                                               int src_col0, int ncols) {
  __shared__ ushort T[64][66];
  const int c0 = blockIdx.x*64, l0 = blockIdx.y*64, bc = blockIdx.z;
  const int t = threadIdx.x;
  const int base = bc*CH;
  for (int i = t; i < 4096; i += 256) {
    int lr = i>>6, cc = i&63;
    T[lr][cc] = xcb[(size_t)(base+l0+lr)*CDIM + src_col0 + c0+cc];
  }
  __syncthreads();
  for (int i = t; i < 4096; i += 256) {
    int cc = i>>6, lr = i&63;
    dst[((size_t)bc*ncols + c0+cc)*CH + l0+lr] = T[lr][cc];
  }
}

// ---------- in-proj GEMM (bf16 MFMA) -> bf16 zxb ----------
__global__ __launch_bounds__(256) void k_gemm_in_mfma(const ushort* __restrict__ xbf,
                                                      const ushort* __restrict__ wbf,
                                                      ushort* __restrict__ zxb) {
  __shared__ ushort As[128*40];
  __shared__ ushort Bs[64*40];
  const int tid = threadIdx.x;
  const int n0 = blockIdx.x*64, m0 = blockIdx.y*128;
  const int wave = tid>>6, lane = tid&63;
  const int lr = lane&15, quad = lane>>4;
  const int KK = DM;
  f32x4 acc[2][4];
#pragma unroll
  for (int mi=0;mi<2;++mi)
#pragma unroll
    for (int ni=0;ni<4;++ni)
#pragma unroll
      for (int r=0;r<4;++r) acc[mi][ni][r] = 0.f;
  const int srow = tid>>2, sc = tid&3;
  for (int k0 = 0; k0 < KK; k0 += 32) {
    *(uint4*)&As[srow*40 + sc*8]      = *(const uint4*)(xbf + (size_t)(m0+srow)*KK    + k0 + sc*8);
    *(uint4*)&As[(srow+64)*40 + sc*8] = *(const uint4*)(xbf + (size_t)(m0+srow+64)*KK + k0 + sc*8);
    *(uint4*)&Bs[srow*40 + sc*8]      = *(const uint4*)(wbf + (size_t)(n0+srow)*KK    + k0 + sc*8);
    __syncthreads();
    bf16x8 af[2], bfr[4];
    const int ar = wave*32 + lr;
    af[0] = *(const bf16x8*)&As[ar*40 + quad*8];
    af[1] = *(const bf16x8*)&As[(ar+16)*40 + quad*8];
#pragma unroll
    for (int ni=0;ni<4;++ni) bfr[ni] = *(const bf16x8*)&Bs[(ni*16+lr)*40 + quad*8];
#pragma unroll
    for (int mi=0;mi<2;++mi)
#pragma unroll
      for (int ni=0;ni<4;++ni)
        acc[mi][ni] = __builtin_amdgcn_mfma_f32_16x16x32_bf16(af[mi], bfr[ni], acc[mi][ni], 0, 0, 0);
    __syncthreads();
  }
#pragma unroll
  for (int mi=0;mi<2;++mi) {
    int m = m0 + wave*32 + mi*16 + quad*4;
#pragma unroll
    for (int ni=0;ni<4;++ni) {
      int n = n0 + ni*16 + lr;
#pragma unroll
      for (int r=0;r<4;++r) zxb[(size_t)(m+r)*NZX + n] = f2bf(acc[mi][ni][r]);
    }
  }
}

// ---------- dt exact fp32 ----------
__global__ __launch_bounds__(256) void k_dt_direct(const float* __restrict__ x,
                                                   const float* __restrict__ W,
                                                   const float* __restrict__ dt_bias,
                                                   float* __restrict__ dtb) {
  __shared__ float Xs[256][16];
  __shared__ float Ws[16][257];
  const int t = threadIdx.x;
  const int bm = blockIdx.x*16;
  const int b = bm >> 10, l0 = bm & 1023;
  for (int i = t; i < 4096; i += 256) {
    int h = i>>8, k = i&255;
    Ws[h][k] = W[(size_t)(NZX+h)*DM + k];
  }
  for (int i = t; i < 4096; i += 256) {
    int k = i>>4, li = i&15;
    Xs[k][li] = x[(size_t)b*DM*L_ + (size_t)k*L_ + l0+li];
  }
  __syncthreads();
  const int h = t&15, li = t>>4;
  float acc = 0.f;
#pragma unroll 8
  for (int k = 0; k < 256; ++k) acc += Xs[k][li]*Ws[h][k];
  float v = acc + dt_bias[h];
  dtb[(size_t)bm*NH + t] = (v > 20.f) ? v : log1pf(expf(v));
}

// ---------- conv4 + SiLU -> bf16 xcb ----------
__global__ __launch_bounds__(256) void k_conv(const ushort* __restrict__ zxb,
                                              const float* __restrict__ cw,
                                              const float* __restrict__ cb,
                                              ushort* __restrict__ xcb) {
  const int j = blockIdx.x*256 + threadIdx.x;          // 0..767
  const int l0 = (blockIdx.y*4) & 1023;
  const int mb = (blockIdx.y*4) & ~1023;               // b*1024
  const float4 w = *(const float4*)&cw[j*4];
  const float bias = cb[j];
  float v[7];
#pragma unroll
  for (int i = 0; i < 7; ++i) {
    int ll = l0 - 3 + i;
    v[i] = (ll >= 0) ? bf2f(zxb[(size_t)(mb+ll)*NZX + DI + j]) : 0.f;
  }
#pragma unroll
  for (int i = 0; i < 4; ++i) {
    float a = bias + w.x*v[i] + w.y*v[i+1] + w.z*v[i+2] + w.w*v[i+3];
    a = a / (1.f + expf(-a));
    xcb[(size_t)(mb+l0+i)*CDIM + j] = f2bf(a);
  }
}

// ---------- S0b = Cm·Bm^T (bf16 MFMA, lower-triangular tiles only) ----------
__global__ __launch_bounds__(256) void k_s0_mfma(const ushort* __restrict__ xcb,
                                                 ushort* __restrict__ S0b) {
  const int lt = blockIdx.x, st = blockIdx.y, bc = blockIdx.z;
  if (st > lt) return;
  const int base = bc*CH;
  const int t = threadIdx.x;
  const int wave = t>>6, lane = t&63, lr = lane&15, quad = lane>>4;
  const int l = lt*64 + wave*16 + lr;
  f32x4 acc[4];
#pragma unroll
  for (int nt = 0; nt < 4; ++nt)
#pragma unroll
    for (int r = 0; r < 4; ++r) acc[nt][r] = 0.f;
#pragma unroll
  for (int ks = 0; ks < 4; ++ks) {
    bf16x8 af = *(const bf16x8*)(xcb + (size_t)(base+l)*CDIM + (DI+DS) + ks*32 + quad*8);
#pragma unroll
    for (int nt = 0; nt < 4; ++nt) {
      bf16x8 bf = *(const bf16x8*)(xcb + (size_t)(base + st*64 + nt*16 + lr)*CDIM + DI + ks*32 + quad*8);
      acc[nt] = __builtin_amdgcn_mfma_f32_16x16x32_bf16(af, bf, acc[nt], 0, 0, 0);
    }
  }
#pragma unroll
  for (int nt = 0; nt < 4; ++nt)
#pragma unroll
    for (int r = 0; r < 4; ++r)
      S0b[((size_t)bc*CH + lt*64 + wave*16 + quad*4 + r)*CH + st*64 + nt*16 + lr] = f2bf(acc[nt][r]);
}

// ---------- per (b,c,h): cumsum + chunk states via MFMA ----------
// st[p][n] = sum_l (X[l][p]*wv[l]) * B[l][n];  A = Xw (LDS, in-kernel transpose), B = B^T (global)
__global__ __launch_bounds__(256) void k_states_mfma(const ushort* __restrict__ xcb,
                                                     const ushort* __restrict__ btg,
                                                     const float* __restrict__ dtb,
                                                     const float* __restrict__ A_log,
                                                     float* __restrict__ acs_g,
                                                     float* __restrict__ st) {
  __shared__ float acs[CH];
  __shared__ ushort Xw[32][264];
  const int t = threadIdx.x;
  const int bc = blockIdx.x, h = blockIdx.y;
  const int base = bc*CH;
  float dt_t = dtb[(size_t)(base+t)*NH + h];
  float An = -expf(A_log[h]);
  acs[t] = dt_t * An;
  __syncthreads();
  for (int off = 1; off < CH; off <<= 1) {
    float v = (t >= off) ? acs[t-off] : 0.f;
    __syncthreads();
    acs[t] += v;
    __syncthreads();
  }
  float alast = acs[CH-1];
  acs_g[((size_t)bc*NH + h)*CH + t] = acs[t];
  float w = expf(alast - acs[t]) * dt_t;       // thread-local: wv[l=t]
  // stage Xw[p][t] = X[t][p] * wv[t]  (transpose through LDS)
  {
    const ushort* xp = xcb + (size_t)(base+t)*CDIM + h*HD;
    ushort tmp[32];
    *(uint4*)&tmp[0]  = *(const uint4*)(xp);
    *(uint4*)&tmp[8]  = *(const uint4*)(xp+8);
    *(uint4*)&tmp[16] = *(const uint4*)(xp+16);
    *(uint4*)&tmp[24] = *(const uint4*)(xp+24);
#pragma unroll
    for (int p = 0; p < 32; ++p) Xw[p][t] = f2bf(bf2f(tmp[p]) * w);
  }
  __syncthreads();
  const int wave = t>>6, lane = t&63, lr = lane&15, quad = lane>>4;
  f32x4 acc[2][2];
#pragma unroll
  for (int mt=0;mt<2;++mt)
#pragma unroll
    for (int nt=0;nt<2;++nt)
#pragma unroll
      for (int r=0;r<4;++r) acc[mt][nt][r] = 0.f;
  const ushort* bp = btg + (size_t)bc*DS*CH;
#pragma unroll
  for (int k0 = 0; k0 < CH; k0 += 32) {
    bf16x8 a0 = *(const bf16x8*)&Xw[lr][k0 + quad*8];
    bf16x8 a1 = *(const bf16x8*)&Xw[16+lr][k0 + quad*8];
    bf16x8 b0 = *(const bf16x8*)(bp + (size_t)(wave*32 + lr)*CH + k0 + quad*8);
    bf16x8 b1 = *(const bf16x8*)(bp + (size_t)(wave*32 + 16 + lr)*CH + k0 + quad*8);
    acc[0][0] = __builtin_amdgcn_mfma_f32_16x16x32_bf16(a0, b0, acc[0][0], 0,0,0);
    acc[0][1] = __builtin_amdgcn_mfma_f32_16x16x32_bf16(a0, b1, acc[0][1], 0,0,0);
    acc[1][0] = __builtin_amdgcn_mfma_f32_16x16x32_bf16(a1, b0, acc[1][0], 0,0,0);
    acc[1][1] = __builtin_amdgcn_mfma_f32_16x16x32_bf16(a1, b1, acc[1][1], 0,0,0);
  }
  size_t sb = ((size_t)bc*NH + h)*HD*DS;
#pragma unroll
  for (int mt = 0; mt < 2; ++mt)
#pragma unroll
    for (int nt = 0; nt < 2; ++nt)
#pragma unroll
      for (int r = 0; r < 4; ++r)
        st[sb + (size_t)(mt*16 + quad*4 + r)*DS + wave*32 + nt*16 + lr] = acc[mt][nt][r];
}

// ---------- inter-chunk scan ----------
__global__ void k_scan(const float* __restrict__ acs_g, const float* __restrict__ st,
                       float* __restrict__ pv) {
  const int b = blockIdx.x, h = blockIdx.y;
  const int t = threadIdx.x;
  float P[16];
#pragma unroll
  for (int i = 0; i < 16; ++i) P[i] = 0.f;
  for (int c = 0; c < NC; ++c) {
    size_t sb = ((size_t)(b*NC+c)*NH + h)*HD*DS;
    float T = acs_g[((size_t)(b*NC+c)*NH + h)*CH + (CH-1)];
    float ec = expf(T);
#pragma unroll
    for (int i = 0; i < 16; ++i) {
      size_t e = sb + (size_t)i*256 + t;
      pv[e] = P[i];
      P[i] = st[e] + ec * P[i];
    }
  }
}

// ---------- Y = Y_diag + Y_off + D*xs (MFMA) -> bf16 ----------
__global__ __launch_bounds__(256) void k_y_mfma(const ushort* __restrict__ xcb,
    const float* __restrict__ dtb, const float* __restrict__ acs_g,
    const ushort* __restrict__ S0b, const float* __restrict__ pv,
    const float* __restrict__ Dp, ushort* __restrict__ Yb) {
  __shared__ ushort Xt[32][280];
  __shared__ float acs[CH];
  __shared__ float dts[CH];
  __shared__ float E8[CH];
  const int t = threadIdx.x;
  const int bc = blockIdx.x, h = blockIdx.y;
  const int base = bc*CH;
  acs[t] = acs_g[((size_t)bc*NH + h)*CH + t];
  dts[t] = dtb[(size_t)(base+t)*NH + h];
  {
    const ushort* xp = xcb + (size_t)(base+t)*CDIM + h*HD;
    ushort tmp[32];
    *(uint4*)&tmp[0]  = *(const uint4*)(xp);
    *(uint4*)&tmp[8]  = *(const uint4*)(xp+8);
    *(uint4*)&tmp[16] = *(const uint4*)(xp+16);
    *(uint4*)&tmp[24] = *(const uint4*)(xp+24);
#pragma unroll
    for (int p = 0; p < 32; ++p) Xt[p][t] = tmp[p];
  }
  __syncthreads();
  E8[t] = expf(acs[t & ~7] - acs[t]) * dts[t];
  __syncthreads();
  const int wave = t>>6, lane = t&63, lr = lane&15, quad = lane>>4;
  f32x4 acc[4][2];
#pragma unroll
  for (int mt=0;mt<4;++mt)
#pragma unroll
    for (int nt=0;nt<2;++nt)
#pragma unroll
      for (int r=0;r<4;++r) acc[mt][nt][r] = 0.f;
  const size_t pb = ((size_t)bc*NH + h)*HD*DS;
#pragma unroll
  for (int ks = 0; ks < 4; ++ks) {
    bf16x8 bfr[2];
#pragma unroll
    for (int nt = 0; nt < 2; ++nt) {
      const float* pp = pv + pb + (size_t)(nt*16+lr)*DS + ks*32 + quad*8;
      float4 v0 = *(const float4*)pp;
      float4 v1 = *(const float4*)(pp+4);
      bf16x8 bb;
      bb[0]=(short)f2bf(v0.x); bb[1]=(short)f2bf(v0.y); bb[2]=(short)f2bf(v0.z); bb[3]=(short)f2bf(v0.w);
      bb[4]=(short)f2bf(v1.x); bb[5]=(short)f2bf(v1.y); bb[6]=(short)f2bf(v1.z); bb[7]=(short)f2bf(v1.w);
      bfr[nt] = bb;
    }
#pragma unroll
    for (int mt = 0; mt < 4; ++mt) {
      int l = wave*64 + mt*16 + lr;
      bf16x8 af = *(const bf16x8*)(xcb + (size_t)(base+l)*CDIM + (DI+DS) + ks*32 + quad*8);
      acc[mt][0] = __builtin_amdgcn_mfma_f32_16x16x32_bf16(af, bfr[0], acc[mt][0], 0,0,0);
      acc[mt][1] = __builtin_amdgcn_mfma_f32_16x16x32_bf16(af, bfr[1], acc[mt][1], 0,0,0);
    }
  }
#pragma unroll
  for (int mt = 0; mt < 4; ++mt)
#pragma unroll
    for (int r = 0; r < 4; ++r) {
      float e = expf(acs[wave*64 + mt*16 + quad*4 + r]);
      acc[mt][0][r] *= e;
      acc[mt][1][r] *= e;
    }
  float al[4];
#pragma unroll
  for (int mt = 0; mt < 4; ++mt) al[mt] = acs[wave*64 + mt*16 + lr];
  const int km3 = 2*wave + 1;
  for (int ks = 0; ks <= km3; ++ks) {
    const int sq = ks*32 + quad*8;
    const float as0 = acs[sq];
    const float4 e0 = *(const float4*)&E8[sq];
    const float4 e1 = *(const float4*)&E8[sq+4];
    const bf16x8 xb0 = *(const bf16x8*)&Xt[lr][sq];
    const bf16x8 xb1 = *(const bf16x8*)&Xt[16+lr][sq];
    const float ev[8] = {e0.x,e0.y,e0.z,e0.w,e1.x,e1.y,e1.z,e1.w};
#pragma unroll
    for (int mt = 0; mt < 4; ++mt) {
      if (ks > ((wave*64 + mt*16 + 15) >> 5)) continue;
      const int l = wave*64 + mt*16 + lr;
      const bf16x8 sb = *(const bf16x8*)(S0b + ((size_t)bc*CH + l)*CH + sq);
      const float el = expf(al[mt] - as0);
      bf16x8 mf;
#pragma unroll
      for (int j = 0; j < 8; ++j) {
        float v = (sq + j <= l) ? bf2f((ushort)sb[j]) * el * ev[j] : 0.f;
        mf[j] = (short)f2bf(v);
      }
      acc[mt][0] = __builtin_amdgcn_mfma_f32_16x16x32_bf16(mf, xb0, acc[mt][0], 0,0,0);
      acc[mt][1] = __builtin_amdgcn_mfma_f32_16x16x32_bf16(mf, xb1, acc[mt][1], 0,0,0);
    }
  }
  const float dph = Dp[h];
#pragma unroll
  for (int mt = 0; mt < 4; ++mt) {
    const int lb = wave*64 + mt*16 + quad*4;
#pragma unroll
    for (int nt = 0; nt < 2; ++nt) {
      const int p = nt*16 + lr;
#pragma unroll
      for (int r = 0; r < 4; ++r) {
        float xv = bf2f(Xt[p][lb+r]);
        Yb[(size_t)(base+lb+r)*DI + h*HD + p] = f2bf(acc[mt][nt][r] + dph*xv);
      }
    }
  }
}

// ---------- gate + RMSNorm, bf16 in/out ----------
__global__ __launch_bounds__(256) void k_rms(const ushort* __restrict__ zxb,
                                             const ushort* __restrict__ Yb,
                                             const float* __restrict__ rw,
                                             ushort* __restrict__ yn) {
  const int m = blockIdx.x, t = threadIdx.x;
  float z0 = bf2f(zxb[(size_t)m*NZX + t]);
  float z1 = bf2f(zxb[(size_t)m*NZX + t + 256]);
  float y0 = bf2f(Yb[(size_t)m*DI + t])       * z0 / (1.f + expf(-z0));
  float y1 = bf2f(Yb[(size_t)m*DI + t + 256]) * z1 / (1.f + expf(-z1));
  float ss = y0*y0 + y1*y1;
#pragma unroll
  for (int off = 32; off > 0; off >>= 1) ss += __shfl_down(ss, off);
  __shared__ float red[4];
  __shared__ float sinv;
  if ((t & 63) == 0) red[t >> 6] = ss;
  __syncthreads();
  if (t == 0) sinv = rsqrtf((red[0]+red[1]+red[2]+red[3]) * (1.f/DI) + EPSV);
  __syncthreads();
  float inv = sinv;
  yn[(size_t)m*DI + t]       = f2bf(y0 * inv * rw[t]);
  yn[(size_t)m*DI + t + 256] = f2bf(y1 * inv * rw[t+256]);
}

// ---------- out-proj GEMM (bf16 MFMA) + GN partial sums via atomics ----------
__global__ __launch_bounds__(256) void k_gemm_out_mfma(const ushort* __restrict__ ynbf,
                                                       const ushort* __restrict__ wobf,
                                                       float* __restrict__ outp,
                                                       float2* __restrict__ gnp) {
  __shared__ ushort As[128*40];
  __shared__ ushort Bs[64*40];
  const int tid = threadIdx.x;
  const int n0 = blockIdx.x*64, m0 = blockIdx.y*128;
  const int wave = tid>>6, lane = tid&63;
  const int lr = lane&15, quad = lane>>4;
  const int KK = DI;
  f32x4 acc[2][4];
#pragma unroll
  for (int mi=0;mi<2;++mi)
#pragma unroll
    for (int ni=0;ni<4;++ni)
#pragma unroll
      for (int r=0;r<4;++r) acc[mi][ni][r] = 0.f;
  const int srow = tid>>2, sc = tid&3;
  for (int k0 = 0; k0 < KK; k0 += 32) {
    *(uint4*)&As[srow*40 + sc*8]      = *(const uint4*)(ynbf + (size_t)(m0+srow)*KK    + k0 + sc*8);
    *(uint4*)&As[(srow+64)*40 + sc*8] = *(const uint4*)(ynbf + (size_t)(m0+srow+64)*KK + k0 + sc*8);
    *(uint4*)&Bs[srow*40 + sc*8]      = *(const uint4*)(wobf + (size_t)(n0+srow)*KK    + k0 + sc*8);
    __syncthreads();
    bf16x8 af[2], bfr[4];
    const int ar = wave*32 + lr;
    af[0] = *(const bf16x8*)&As[ar*40 + quad*8];
    af[1] = *(const bf16x8*)&As[(ar+16)*40 + quad*8];
#pragma unroll
    for (int ni=0;ni<4;++ni) bfr[ni] = *(const bf16x8*)&Bs[(ni*16+lr)*40 + quad*8];
#pragma unroll
    for (int mi=0;mi<2;++mi)
#pragma unroll
      for (int ni=0;ni<4;++ni)
        acc[mi][ni] = __builtin_amdgcn_mfma_f32_16x16x32_bf16(af[mi], bfr[ni], acc[mi][ni], 0, 0, 0);
    __syncthreads();
  }
  const int b = m0 >> 10, l0 = m0 & 1023;
  float s0=0.f, ss0=0.f, s1=0.f, ss1=0.f;
#pragma unroll
  for (int mi=0;mi<2;++mi) {
    int lb = l0 + wave*32 + mi*16 + quad*4;
#pragma unroll
    for (int ni=0;ni<4;++ni) {
      int n = n0 + ni*16 + lr;
      float4 v = make_float4(acc[mi][ni][0], acc[mi][ni][1], acc[mi][ni][2], acc[mi][ni][3]);
      *(float4*)&outp[(size_t)b*DM*L_ + (size_t)n*L_ + lb] = v;
      float ps = v.x+v.y+v.z+v.w;
      float pq = v.x*v.x+v.y*v.y+v.z*v.z+v.w*v.w;
      if (ni < 2) { s0 += ps; ss0 += pq; } else { s1 += ps; ss1 += pq; }
    }
  }
#pragma unroll
  for (int off = 32; off > 0; off >>= 1) {
    s0 += __shfl_down(s0, off); ss0 += __shfl_down(ss0, off);
    s1 += __shfl_down(s1, off); ss1 += __shfl_down(ss1, off);
  }
  __shared__ float red[4][4];
  if (lane == 0) { red[wave][0]=s0; red[wave][1]=ss0; red[wave][2]=s1; red[wave][3]=ss1; }
  __syncthreads();
  if (tid == 0) {
    float S0=0,Q0=0,S1=0,Q1=0;
#pragma unroll
    for (int wv2 = 0; wv2 < 4; ++wv2) { S0+=red[wv2][0]; Q0+=red[wv2][1]; S1+=red[wv2][2]; Q1+=red[wv2][3]; }
    int g0 = b*8 + (n0>>5);
    atomicAdd(&gnp[g0].x, S0);   atomicAdd(&gnp[g0].y, Q0);
    atomicAdd(&gnp[g0+1].x, S1); atomicAdd(&gnp[g0+1].y, Q1);
  }
}

// ---------- GroupNorm apply + Mish (stats computed inline from gnp) ----------
__global__ __launch_bounds__(256) void k_gn_apply(const float2* __restrict__ gnp,
                                                  const float* __restrict__ gw,
                                                  const float* __restrict__ gb,
                                                  float* __restrict__ o) {
  const int ch = blockIdx.x & 255, b = blockIdx.x >> 8;
  const int t = threadIdx.x;
  float2 p = gnp[b*8 + (ch>>5)];
  const float mean = p.x * (1.f/(32.f*L_));
  const float var  = p.y * (1.f/(32.f*L_)) - mean*mean;
  const float inv  = rsqrtf(var + EPSV);
  const float w = gw[ch], bb = gb[ch];
  size_t base = (size_t)blockIdx.x * L_;
  float4 v = *(const float4*)&o[base + t*4];
  float r[4] = {v.x, v.y, v.z, v.w};
#pragma unroll
  for (int j = 0; j < 4; ++j) {
    float u = (r[j] - mean) * inv * w + bb;
    float m;
    if (u > 15.f) m = u;
    else {
      float e = expf(u);
      float a = 1.f + e;
      float a2 = a*a;
      m = u * (a2 - 1.f) / (a2 + 1.f);
    }
    r[j] = m;
  }
  *(float4*)&o[base + t*4] = make_float4(r[0], r[1], r[2], r[3]);
}

extern "C" void kernel_launch(void* const* d_in, const int* in_sizes, int n_in,
                              void* d_out, int out_size, void* d_ws, size_t ws_size,
                              hipStream_t stream) {
  const float* x       = (const float*)d_in[0];
  const float* W_in    = (const float*)d_in[1];
  const float* conv_w  = (const float*)d_in[2];
  const float* conv_b  = (const float*)d_in[3];
  const float* dt_bias = (const float*)d_in[4];
  const float* A_log   = (const float*)d_in[5];
  const float* Dp      = (const float*)d_in[6];
  const float* rms_w   = (const float*)d_in[7];
  const float* W_out   = (const float*)d_in[8];
  const float* gn_w    = (const float*)d_in[9];
  const float* gn_b    = (const float*)d_in[10];
  float* out = (float*)d_out;
  float* ws  = (float*)d_ws;

  ushort* zxb   = (ushort*)(ws + OFF_ZX);
  ushort* xcb   = (ushort*)(ws + OFF_XC);
  float*  dtb   = ws + OFF_DT;
  float*  acs   = ws + OFF_ACS;
  ushort* S0b   = (ushort*)(ws + OFF_S0);
  float*  st    = ws + OFF_ST;
  float*  pv    = ws + OFF_PV;
  ushort* Ybb   = (ushort*)(ws + OFF_Y);
  ushort* ynbf  = (ushort*)(ws + OFF_YNB);
  ushort* xbf   = (ushort*)(ws + OFF_XBF);
  ushort* wbf   = (ushort*)(ws + OFF_WBF);
  ushort* wobf  = (ushort*)(ws + OFF_WOBF);
  float2* gnp   = (float2*)(ws + OFF_GNP);
  ushort* btg   = (ushort*)(ws + OFF_BT);

  k_zero_gnp     <<<dim3(1), 64, 0, stream>>>(gnp);
  k_cast_x       <<<dim3(4, 16, 8), 256, 0, stream>>>(x, xbf);
  k_cast         <<<dim3((1296*DM+255)/256), 256, 0, stream>>>(W_in, wbf, 1296*DM);
  k_cast         <<<dim3((DM*DI+255)/256), 256, 0, stream>>>(W_out, wobf, DM*DI);
  k_gemm_in_mfma <<<dim3(NZX/64, M_/128), 256, 0, stream>>>(xbf, wbf, zxb);
  k_dt_direct    <<<dim3(M_/16), 256, 0, stream>>>(x, W_in, dt_bias, dtb);
  k_conv         <<<dim3(3, M_/4), 256, 0, stream>>>(zxb, conv_w, conv_b, xcb);
  k_xpose        <<<dim3(2, 4, B_*NC), 256, 0, stream>>>(xcb, btg, DI, DS);
  k_s0_mfma      <<<dim3(4, 4, B_*NC), 256, 0, stream>>>(xcb, S0b);
  k_states_mfma  <<<dim3(B_*NC, NH), 256, 0, stream>>>(xcb, btg, dtb, A_log, acs, st);
  k_scan         <<<dim3(B_, NH), 256, 0, stream>>>(acs, st, pv);
  k_y_mfma       <<<dim3(B_*NC, NH), 256, 0, stream>>>(xcb, dtb, acs, S0b, pv, Dp, Ybb);
  k_rms          <<<dim3(M_), 256, 0, stream>>>(zxb, Ybb, rms_w, ynbf);
  k_gemm_out_mfma<<<dim3(DM/64, M_/128), 256, 0, stream>>>(ynbf, wobf, out, gnp);
  k_gn_apply     <<<dim3(B_*DM), 256, 0, stream>>>(gnp, gn_w, gn_b, out);
}

// Round 7
// 191.904 us; speedup vs baseline: 3.2075x; 1.0286x over previous
//
#include <hip/hip_runtime.h>
#include <hip/hip_bf16.h>
#include <math.h>

#define B_ 8
#define L_ 1024
#define DM 256
#define DI 512
#define HD 32
#define NH 16
#define DS 128
#define CDIM 768
#define NZX 1280    // z + xBC cols (dt computed separately)
#define CH 256
#define NC 4
#define M_ (B_*L_)
#define EPSV 1e-5f

typedef short bf16x8 __attribute__((ext_vector_type(8)));
typedef float f32x4 __attribute__((ext_vector_type(4)));

// ---- workspace layout (float units) ----
#define OFF_ZX   0                         // M_*NZX bf16
#define SZ_ZX    (M_*NZX/2)
#define OFF_XC   (OFF_ZX+SZ_ZX)            // M_*CDIM bf16
#define SZ_XC    (M_*CDIM/2)
#define OFF_DT   (OFF_XC+SZ_XC)            // M_*NH fp32
#define SZ_DT    (M_*NH)
#define OFF_ACS  (OFF_DT+SZ_DT)
#define SZ_ACS   (B_*NC*NH*CH)
#define OFF_S0   (OFF_ACS+SZ_ACS)          // bf16 S0b
#define SZ_S0    (B_*NC*CH*CH/2)
#define OFF_ST   (OFF_S0+SZ_S0)
#define SZ_ST    (B_*NC*NH*HD*DS)
#define OFF_PV   (OFF_ST+SZ_ST)
#define SZ_PV    SZ_ST
#define OFF_Y    (OFF_PV+SZ_PV)            // M_*DI bf16
#define SZ_Y     (M_*DI/2)
#define OFF_YNB  (OFF_Y+SZ_Y)              // M_*DI bf16
#define SZ_YNB   (M_*DI/2)
#define OFF_XBF  (OFF_YNB+SZ_YNB)          // M_*DM bf16
#define SZ_XBF   (M_*DM/2)
#define OFF_WBF  (OFF_XBF+SZ_XBF)          // 1296*DM bf16
#define SZ_WBF   (1296*DM/2)
#define OFF_WOBF (OFF_WBF+SZ_WBF)          // DM*DI bf16
#define SZ_WOBF  (DM*DI/2)
#define OFF_GNP  (OFF_WOBF+SZ_WOBF)        // 64 float2 group accumulators
#define SZ_GNP   (64*2)
#define OFF_BT   (OFF_GNP+SZ_GNP)          // B^T: 32*128*256 bf16
#define SZ_BT    (32*128*256/2)
#define OFF_OUTB (OFF_BT+SZ_BT)            // pre-GN out bf16: M_*DM
#define SZ_OUTB  (M_*DM/2)

__device__ __forceinline__ ushort f2bf(float v) {
  __hip_bfloat16 h = __float2bfloat16(v);
  return *(ushort*)&h;
}
__device__ __forceinline__ float bf2f(ushort u) {
  return __uint_as_float(((unsigned int)u) << 16);
}

// ---------- fused prep: cast_x transpose + W casts + gnp zero ----------
__global__ __launch_bounds__(256) void k_prep(const float* __restrict__ x,
                                              const float* __restrict__ W_in,
                                              const float* __restrict__ W_out,
                                              ushort* __restrict__ xbf,
                                              ushort* __restrict__ wbf,
                                              ushort* __restrict__ wobf,
                                              float2* __restrict__ gnp) {
  __shared__ float Ts[64][65];
  const int bid = blockIdx.x;
  const int t = threadIdx.x;
  if (bid < 512) {
    // x[b][k][l] -> xbf[b*L+l][k]
    const int kt = bid & 3, lt = (bid >> 2) & 15, b = bid >> 6;
    const int k0 = kt*64, l0 = lt*64;
    for (int i = t; i < 4096; i += 256) {
      int kk = i>>6, ll = i&63;
      Ts[kk][ll] = x[(size_t)b*DM*L_ + (size_t)(k0+kk)*L_ + l0+ll];
    }
    __syncthreads();
    for (int i = t; i < 4096; i += 256) {
      int mm = i>>6, kk = i&63;
      xbf[(size_t)(b*L_ + l0+mm)*DM + k0+kk] = f2bf(Ts[kk][mm]);
    }
  } else if (bid < 512 + 1296) {
    int i = (bid-512)*256 + t;
    if (i < 1296*DM) wbf[i] = f2bf(W_in[i]);
  } else if (bid < 512 + 1296 + 512) {
    int i = (bid-512-1296)*256 + t;
    wobf[i] = f2bf(W_out[i]);
  } else {
    if (t < 64) gnp[t] = make_float2(0.f, 0.f);
  }
}

// ---------- in-proj GEMM (bf16 MFMA) -> bf16 zxb ----------
__global__ __launch_bounds__(256) void k_gemm_in_mfma(const ushort* __restrict__ xbf,
                                                      const ushort* __restrict__ wbf,
                                                      ushort* __restrict__ zxb) {
  __shared__ ushort As[128*40];
  __shared__ ushort Bs[64*40];
  const int tid = threadIdx.x;
  const int n0 = blockIdx.x*64, m0 = blockIdx.y*128;
  const int wave = tid>>6, lane = tid&63;
  const int lr = lane&15, quad = lane>>4;
  const int KK = DM;
  f32x4 acc[2][4];
#pragma unroll
  for (int mi=0;mi<2;++mi)
#pragma unroll
    for (int ni=0;ni<4;++ni)
#pragma unroll
      for (int r=0;r<4;++r) acc[mi][ni][r] = 0.f;
  const int srow = tid>>2, sc = tid&3;
  for (int k0 = 0; k0 < KK; k0 += 32) {
    *(uint4*)&As[srow*40 + sc*8]      = *(const uint4*)(xbf + (size_t)(m0+srow)*KK    + k0 + sc*8);
    *(uint4*)&As[(srow+64)*40 + sc*8] = *(const uint4*)(xbf + (size_t)(m0+srow+64)*KK + k0 + sc*8);
    *(uint4*)&Bs[srow*40 + sc*8]      = *(const uint4*)(wbf + (size_t)(n0+srow)*KK    + k0 + sc*8);
    __syncthreads();
    bf16x8 af[2], bfr[4];
    const int ar = wave*32 + lr;
    af[0] = *(const bf16x8*)&As[ar*40 + quad*8];
    af[1] = *(const bf16x8*)&As[(ar+16)*40 + quad*8];
#pragma unroll
    for (int ni=0;ni<4;++ni) bfr[ni] = *(const bf16x8*)&Bs[(ni*16+lr)*40 + quad*8];
#pragma unroll
    for (int mi=0;mi<2;++mi)
#pragma unroll
      for (int ni=0;ni<4;++ni)
        acc[mi][ni] = __builtin_amdgcn_mfma_f32_16x16x32_bf16(af[mi], bfr[ni], acc[mi][ni], 0, 0, 0);
    __syncthreads();
  }
#pragma unroll
  for (int mi=0;mi<2;++mi) {
    int m = m0 + wave*32 + mi*16 + quad*4;
#pragma unroll
    for (int ni=0;ni<4;++ni) {
      int n = n0 + ni*16 + lr;
#pragma unroll
      for (int r=0;r<4;++r) zxb[(size_t)(m+r)*NZX + n] = f2bf(acc[mi][ni][r]);
    }
  }
}

// ---------- dt exact fp32 ----------
__global__ __launch_bounds__(256) void k_dt_direct(const float* __restrict__ x,
                                                   const float* __restrict__ W,
                                                   const float* __restrict__ dt_bias,
                                                   float* __restrict__ dtb) {
  __shared__ float Xs[256][16];
  __shared__ float Ws[16][257];
  const int t = threadIdx.x;
  const int bm = blockIdx.x*16;
  const int b = bm >> 10, l0 = bm & 1023;
  for (int i = t; i < 4096; i += 256) {
    int h = i>>8, k = i&255;
    Ws[h][k] = W[(size_t)(NZX+h)*DM + k];
  }
  for (int i = t; i < 4096; i += 256) {
    int k = i>>4, li = i&15;
    Xs[k][li] = x[(size_t)b*DM*L_ + (size_t)k*L_ + l0+li];
  }
  __syncthreads();
  const int h = t&15, li = t>>4;
  float acc = 0.f;
#pragma unroll 8
  for (int k = 0; k < 256; ++k) acc += Xs[k][li]*Ws[h][k];
  float v = acc + dt_bias[h];
  dtb[(size_t)bm*NH + t] = (v > 20.f) ? v : log1pf(expf(v));
}

// ---------- conv4 + SiLU -> bf16 xcb (+ direct B^T write) ----------
__global__ __launch_bounds__(256) void k_conv(const ushort* __restrict__ zxb,
                                              const float* __restrict__ cw,
                                              const float* __restrict__ cb,
                                              ushort* __restrict__ xcb,
                                              ushort* __restrict__ btg) {
  const int j = blockIdx.x*256 + threadIdx.x;          // 0..767
  const int m8 = blockIdx.y*8;
  const int l0 = m8 & 1023;
  const int mb = m8 & ~1023;                           // b*1024
  const float4 w = *(const float4*)&cw[j*4];
  const float bias = cb[j];
  float v[11];
#pragma unroll
  for (int i = 0; i < 11; ++i) {
    int ll = l0 - 3 + i;
    v[i] = (ll >= 0) ? bf2f(zxb[(size_t)(mb+ll)*NZX + DI + j]) : 0.f;
  }
  union { ushort u[8]; uint4 q; } res;
#pragma unroll
  for (int i = 0; i < 8; ++i) {
    float a = bias + w.x*v[i] + w.y*v[i+1] + w.z*v[i+2] + w.w*v[i+3];
    a = a / (1.f + expf(-a));
    res.u[i] = f2bf(a);
    xcb[(size_t)(mb+l0+i)*CDIM + j] = res.u[i];
  }
  if (j >= DI && j < DI+DS) {
    const int n = j - DI;
    const int bc = (mb >> 10)*NC + (l0 >> 8);
    const int lc = l0 & 255;
    *(uint4*)&btg[((size_t)bc*DS + n)*CH + lc] = res.q;
  }
}

// ---------- S0b = Cm·Bm^T (bf16 MFMA, lower-triangular tiles only) ----------
__global__ __launch_bounds__(256) void k_s0_mfma(const ushort* __restrict__ xcb,
                                                 ushort* __restrict__ S0b) {
  const int lt = blockIdx.x, st = blockIdx.y, bc = blockIdx.z;
  if (st > lt) return;
  const int base = bc*CH;
  const int t = threadIdx.x;
  const int wave = t>>6, lane = t&63, lr = lane&15, quad = lane>>4;
  const int l = lt*64 + wave*16 + lr;
  f32x4 acc[4];
#pragma unroll
  for (int nt = 0; nt < 4; ++nt)
#pragma unroll
    for (int r = 0; r < 4; ++r) acc[nt][r] = 0.f;
#pragma unroll
  for (int ks = 0; ks < 4; ++ks) {
    bf16x8 af = *(const bf16x8*)(xcb + (size_t)(base+l)*CDIM + (DI+DS) + ks*32 + quad*8);
#pragma unroll
    for (int nt = 0; nt < 4; ++nt) {
      bf16x8 bf = *(const bf16x8*)(xcb + (size_t)(base + st*64 + nt*16 + lr)*CDIM + DI + ks*32 + quad*8);
      acc[nt] = __builtin_amdgcn_mfma_f32_16x16x32_bf16(af, bf, acc[nt], 0, 0, 0);
    }
  }
#pragma unroll
  for (int nt = 0; nt < 4; ++nt)
#pragma unroll
    for (int r = 0; r < 4; ++r)
      S0b[((size_t)bc*CH + lt*64 + wave*16 + quad*4 + r)*CH + st*64 + nt*16 + lr] = f2bf(acc[nt][r]);
}

// ---------- per (b,c,h): cumsum + chunk states via MFMA ----------
__global__ __launch_bounds__(256) void k_states_mfma(const ushort* __restrict__ xcb,
                                                     const ushort* __restrict__ btg,
                                                     const float* __restrict__ dtb,
                                                     const float* __restrict__ A_log,
                                                     float* __restrict__ acs_g,
                                                     float* __restrict__ st) {
  __shared__ float acs[CH];
  __shared__ ushort Xw[32][264];
  const int t = threadIdx.x;
  const int bc = blockIdx.x, h = blockIdx.y;
  const int base = bc*CH;
  float dt_t = dtb[(size_t)(base+t)*NH + h];
  float An = -expf(A_log[h]);
  acs[t] = dt_t * An;
  __syncthreads();
  for (int off = 1; off < CH; off <<= 1) {
    float v = (t >= off) ? acs[t-off] : 0.f;
    __syncthreads();
    acs[t] += v;
    __syncthreads();
  }
  float alast = acs[CH-1];
  acs_g[((size_t)bc*NH + h)*CH + t] = acs[t];
  float w = expf(alast - acs[t]) * dt_t;
  {
    const ushort* xp = xcb + (size_t)(base+t)*CDIM + h*HD;
    ushort tmp[32];
    *(uint4*)&tmp[0]  = *(const uint4*)(xp);
    *(uint4*)&tmp[8]  = *(const uint4*)(xp+8);
    *(uint4*)&tmp[16] = *(const uint4*)(xp+16);
    *(uint4*)&tmp[24] = *(const uint4*)(xp+24);
#pragma unroll
    for (int p = 0; p < 32; ++p) Xw[p][t] = f2bf(bf2f(tmp[p]) * w);
  }
  __syncthreads();
  const int wave = t>>6, lane = t&63, lr = lane&15, quad = lane>>4;
  f32x4 acc[2][2];
#pragma unroll
  for (int mt=0;mt<2;++mt)
#pragma unroll
    for (int nt=0;nt<2;++nt)
#pragma unroll
      for (int r=0;r<4;++r) acc[mt][nt][r] = 0.f;
  const ushort* bp = btg + (size_t)bc*DS*CH;
#pragma unroll
  for (int k0 = 0; k0 < CH; k0 += 32) {
    bf16x8 a0 = *(const bf16x8*)&Xw[lr][k0 + quad*8];
    bf16x8 a1 = *(const bf16x8*)&Xw[16+lr][k0 + quad*8];
    bf16x8 b0 = *(const bf16x8*)(bp + (size_t)(wave*32 + lr)*CH + k0 + quad*8);
    bf16x8 b1 = *(const bf16x8*)(bp + (size_t)(wave*32 + 16 + lr)*CH + k0 + quad*8);
    acc[0][0] = __builtin_amdgcn_mfma_f32_16x16x32_bf16(a0, b0, acc[0][0], 0,0,0);
    acc[0][1] = __builtin_amdgcn_mfma_f32_16x16x32_bf16(a0, b1, acc[0][1], 0,0,0);
    acc[1][0] = __builtin_amdgcn_mfma_f32_16x16x32_bf16(a1, b0, acc[1][0], 0,0,0);
    acc[1][1] = __builtin_amdgcn_mfma_f32_16x16x32_bf16(a1, b1, acc[1][1], 0,0,0);
  }
  size_t sb = ((size_t)bc*NH + h)*HD*DS;
#pragma unroll
  for (int mt = 0; mt < 2; ++mt)
#pragma unroll
    for (int nt = 0; nt < 2; ++nt)
#pragma unroll
      for (int r = 0; r < 4; ++r)
        st[sb + (size_t)(mt*16 + quad*4 + r)*DS + wave*32 + nt*16 + lr] = acc[mt][nt][r];
}

// ---------- inter-chunk scan ----------
__global__ void k_scan(const float* __restrict__ acs_g, const float* __restrict__ st,
                       float* __restrict__ pv) {
  const int b = blockIdx.x, h = blockIdx.y;
  const int t = threadIdx.x;
  float P[16];
#pragma unroll
  for (int i = 0; i < 16; ++i) P[i] = 0.f;
  for (int c = 0; c < NC; ++c) {
    size_t sb = ((size_t)(b*NC+c)*NH + h)*HD*DS;
    float T = acs_g[((size_t)(b*NC+c)*NH + h)*CH + (CH-1)];
    float ec = expf(T);
#pragma unroll
    for (int i = 0; i < 16; ++i) {
      size_t e = sb + (size_t)i*256 + t;
      pv[e] = P[i];
      P[i] = st[e] + ec * P[i];
    }
  }
}

// ---------- Y = Y_diag + Y_off + D*xs (MFMA) -> bf16 ----------
__global__ __launch_bounds__(256) void k_y_mfma(const ushort* __restrict__ xcb,
    const float* __restrict__ dtb, const float* __restrict__ acs_g,
    const ushort* __restrict__ S0b, const float* __restrict__ pv,
    const float* __restrict__ Dp, ushort* __restrict__ Yb) {
  __shared__ ushort Xt[32][280];
  __shared__ float acs[CH];
  __shared__ float dts[CH];
  __shared__ float E8[CH];
  const int t = threadIdx.x;
  const int bc = blockIdx.x, h = blockIdx.y;
  const int base = bc*CH;
  acs[t] = acs_g[((size_t)bc*NH + h)*CH + t];
  dts[t] = dtb[(size_t)(base+t)*NH + h];
  {
    const ushort* xp = xcb + (size_t)(base+t)*CDIM + h*HD;
    ushort tmp[32];
    *(uint4*)&tmp[0]  = *(const uint4*)(xp);
    *(uint4*)&tmp[8]  = *(const uint4*)(xp+8);
    *(uint4*)&tmp[16] = *(const uint4*)(xp+16);
    *(uint4*)&tmp[24] = *(const uint4*)(xp+24);
#pragma unroll
    for (int p = 0; p < 32; ++p) Xt[p][t] = tmp[p];
  }
  __syncthreads();
  E8[t] = expf(acs[t & ~7] - acs[t]) * dts[t];
  __syncthreads();
  const int wave = t>>6, lane = t&63, lr = lane&15, quad = lane>>4;
  f32x4 acc[4][2];
#pragma unroll
  for (int mt=0;mt<4;++mt)
#pragma unroll
    for (int nt=0;nt<2;++nt)
#pragma unroll
      for (int r=0;r<4;++r) acc[mt][nt][r] = 0.f;
  const size_t pb = ((size_t)bc*NH + h)*HD*DS;
#pragma unroll
  for (int ks = 0; ks < 4; ++ks) {
    bf16x8 bfr[2];
#pragma unroll
    for (int nt = 0; nt < 2; ++nt) {
      const float* pp = pv + pb + (size_t)(nt*16+lr)*DS + ks*32 + quad*8;
      float4 v0 = *(const float4*)pp;
      float4 v1 = *(const float4*)(pp+4);
      bf16x8 bb;
      bb[0]=(short)f2bf(v0.x); bb[1]=(short)f2bf(v0.y); bb[2]=(short)f2bf(v0.z); bb[3]=(short)f2bf(v0.w);
      bb[4]=(short)f2bf(v1.x); bb[5]=(short)f2bf(v1.y); bb[6]=(short)f2bf(v1.z); bb[7]=(short)f2bf(v1.w);
      bfr[nt] = bb;
    }
#pragma unroll
    for (int mt = 0; mt < 4; ++mt) {
      int l = wave*64 + mt*16 + lr;
      bf16x8 af = *(const bf16x8*)(xcb + (size_t)(base+l)*CDIM + (DI+DS) + ks*32 + quad*8);
      acc[mt][0] = __builtin_amdgcn_mfma_f32_16x16x32_bf16(af, bfr[0], acc[mt][0], 0,0,0);
      acc[mt][1] = __builtin_amdgcn_mfma_f32_16x16x32_bf16(af, bfr[1], acc[mt][1], 0,0,0);
    }
  }
#pragma unroll
  for (int mt = 0; mt < 4; ++mt)
#pragma unroll
    for (int r = 0; r < 4; ++r) {
      float e = expf(acs[wave*64 + mt*16 + quad*4 + r]);
      acc[mt][0][r] *= e;
      acc[mt][1][r] *= e;
    }
  float al[4];
#pragma unroll
  for (int mt = 0; mt < 4; ++mt) al[mt] = acs[wave*64 + mt*16 + lr];
  const int km3 = 2*wave + 1;
  for (int ks = 0; ks <= km3; ++ks) {
    const int sq = ks*32 + quad*8;
    const float as0 = acs[sq];
    const float4 e0 = *(const float4*)&E8[sq];
    const float4 e1 = *(const float4*)&E8[sq+4];
    const bf16x8 xb0 = *(const bf16x8*)&Xt[lr][sq];
    const bf16x8 xb1 = *(const bf16x8*)&Xt[16+lr][sq];
    const float ev[8] = {e0.x,e0.y,e0.z,e0.w,e1.x,e1.y,e1.z,e1.w};
#pragma unroll
    for (int mt = 0; mt < 4; ++mt) {
      if (ks > ((wave*64 + mt*16 + 15) >> 5)) continue;
      const int l = wave*64 + mt*16 + lr;
      const bf16x8 sb = *(const bf16x8*)(S0b + ((size_t)bc*CH + l)*CH + sq);
      const float el = expf(al[mt] - as0);
      bf16x8 mf;
#pragma unroll
      for (int j = 0; j < 8; ++j) {
        float v = (sq + j <= l) ? bf2f((ushort)sb[j]) * el * ev[j] : 0.f;
        mf[j] = (short)f2bf(v);
      }
      acc[mt][0] = __builtin_amdgcn_mfma_f32_16x16x32_bf16(mf, xb0, acc[mt][0], 0,0,0);
      acc[mt][1] = __builtin_amdgcn_mfma_f32_16x16x32_bf16(mf, xb1, acc[mt][1], 0,0,0);
    }
  }
  const float dph = Dp[h];
#pragma unroll
  for (int mt = 0; mt < 4; ++mt) {
    const int lb = wave*64 + mt*16 + quad*4;
#pragma unroll
    for (int nt = 0; nt < 2; ++nt) {
      const int p = nt*16 + lr;
#pragma unroll
      for (int r = 0; r < 4; ++r) {
        float xv = bf2f(Xt[p][lb+r]);
        Yb[(size_t)(base+lb+r)*DI + h*HD + p] = f2bf(acc[mt][nt][r] + dph*xv);
      }
    }
  }
}

// ---------- gate + RMSNorm, bf16 in/out ----------
__global__ __launch_bounds__(256) void k_rms(const ushort* __restrict__ zxb,
                                             const ushort* __restrict__ Yb,
                                             const float* __restrict__ rw,
                                             ushort* __restrict__ yn) {
  const int m = blockIdx.x, t = threadIdx.x;
  float z0 = bf2f(zxb[(size_t)m*NZX + t]);
  float z1 = bf2f(zxb[(size_t)m*NZX + t + 256]);
  float y0 = bf2f(Yb[(size_t)m*DI + t])       * z0 / (1.f + expf(-z0));
  float y1 = bf2f(Yb[(size_t)m*DI + t + 256]) * z1 / (1.f + expf(-z1));
  float ss = y0*y0 + y1*y1;
#pragma unroll
  for (int off = 32; off > 0; off >>= 1) ss += __shfl_down(ss, off);
  __shared__ float red[4];
  __shared__ float sinv;
  if ((t & 63) == 0) red[t >> 6] = ss;
  __syncthreads();
  if (t == 0) sinv = rsqrtf((red[0]+red[1]+red[2]+red[3]) * (1.f/DI) + EPSV);
  __syncthreads();
  float inv = sinv;
  yn[(size_t)m*DI + t]       = f2bf(y0 * inv * rw[t]);
  yn[(size_t)m*DI + t + 256] = f2bf(y1 * inv * rw[t+256]);
}

// ---------- out-proj GEMM (bf16 MFMA) -> bf16 outb + GN partials ----------
__global__ __launch_bounds__(256) void k_gemm_out_mfma(const ushort* __restrict__ ynbf,
                                                       const ushort* __restrict__ wobf,
                                                       ushort* __restrict__ outb,
                                                       float2* __restrict__ gnp) {
  __shared__ ushort As[128*40];
  __shared__ ushort Bs[64*40];
  const int tid = threadIdx.x;
  const int n0 = blockIdx.x*64, m0 = blockIdx.y*128;
  const int wave = tid>>6, lane = tid&63;
  const int lr = lane&15, quad = lane>>4;
  const int KK = DI;
  f32x4 acc[2][4];
#pragma unroll
  for (int mi=0;mi<2;++mi)
#pragma unroll
    for (int ni=0;ni<4;++ni)
#pragma unroll
      for (int r=0;r<4;++r) acc[mi][ni][r] = 0.f;
  const int srow = tid>>2, sc = tid&3;
  for (int k0 = 0; k0 < KK; k0 += 32) {
    *(uint4*)&As[srow*40 + sc*8]      = *(const uint4*)(ynbf + (size_t)(m0+srow)*KK    + k0 + sc*8);
    *(uint4*)&As[(srow+64)*40 + sc*8] = *(const uint4*)(ynbf + (size_t)(m0+srow+64)*KK + k0 + sc*8);
    *(uint4*)&Bs[srow*40 + sc*8]      = *(const uint4*)(wobf + (size_t)(n0+srow)*KK    + k0 + sc*8);
    __syncthreads();
    bf16x8 af[2], bfr[4];
    const int ar = wave*32 + lr;
    af[0] = *(const bf16x8*)&As[ar*40 + quad*8];
    af[1] = *(const bf16x8*)&As[(ar+16)*40 + quad*8];
#pragma unroll
    for (int ni=0;ni<4;++ni) bfr[ni] = *(const bf16x8*)&Bs[(ni*16+lr)*40 + quad*8];
#pragma unroll
    for (int mi=0;mi<2;++mi)
#pragma unroll
      for (int ni=0;ni<4;++ni)
        acc[mi][ni] = __builtin_amdgcn_mfma_f32_16x16x32_bf16(af[mi], bfr[ni], acc[mi][ni], 0, 0, 0);
    __syncthreads();
  }
  const int b = m0 >> 10, l0 = m0 & 1023;
  float s0=0.f, ss0=0.f, s1=0.f, ss1=0.f;
#pragma unroll
  for (int mi=0;mi<2;++mi) {
    int lb = l0 + wave*32 + mi*16 + quad*4;
#pragma unroll
    for (int ni=0;ni<4;++ni) {
      int n = n0 + ni*16 + lr;
      union { ushort u[4]; uint2 q; } pk;
#pragma unroll
      for (int r=0;r<4;++r) pk.u[r] = f2bf(acc[mi][ni][r]);
      *(uint2*)&outb[(size_t)b*DM*L_ + (size_t)n*L_ + lb] = pk.q;
      float ps = acc[mi][ni][0]+acc[mi][ni][1]+acc[mi][ni][2]+acc[mi][ni][3];
      float pq = acc[mi][ni][0]*acc[mi][ni][0]+acc[mi][ni][1]*acc[mi][ni][1]
               + acc[mi][ni][2]*acc[mi][ni][2]+acc[mi][ni][3]*acc[mi][ni][3];
      if (ni < 2) { s0 += ps; ss0 += pq; } else { s1 += ps; ss1 += pq; }
    }
  }
#pragma unroll
  for (int off = 32; off > 0; off >>= 1) {
    s0 += __shfl_down(s0, off); ss0 += __shfl_down(ss0, off);
    s1 += __shfl_down(s1, off); ss1 += __shfl_down(ss1, off);
  }
  __shared__ float red[4][4];
  if (lane == 0) { red[wave][0]=s0; red[wave][1]=ss0; red[wave][2]=s1; red[wave][3]=ss1; }
  __syncthreads();
  if (tid == 0) {
    float S0=0,Q0=0,S1=0,Q1=0;
#pragma unroll
    for (int wv2 = 0; wv2 < 4; ++wv2) { S0+=red[wv2][0]; Q0+=red[wv2][1]; S1+=red[wv2][2]; Q1+=red[wv2][3]; }
    int g0 = b*8 + (n0>>5);
    atomicAdd(&gnp[g0].x, S0);   atomicAdd(&gnp[g0].y, Q0);
    atomicAdd(&gnp[g0+1].x, S1); atomicAdd(&gnp[g0+1].y, Q1);
  }
}

// ---------- GroupNorm apply + Mish: bf16 in, fp32 out ----------
__global__ __launch_bounds__(256) void k_gn_apply(const float2* __restrict__ gnp,
                                                  const float* __restrict__ gw,
                                                  const float* __restrict__ gb,
                                                  const ushort* __restrict__ ob,
                                                  float* __restrict__ o) {
  const int ch = blockIdx.x & 255, b = blockIdx.x >> 8;
  const int t = threadIdx.x;
  float2 p = gnp[b*8 + (ch>>5)];
  const float mean = p.x * (1.f/(32.f*L_));
  const float var  = p.y * (1.f/(32.f*L_)) - mean*mean;
  const float inv  = rsqrtf(var + EPSV);
  const float w = gw[ch], bb = gb[ch];
  size_t base = (size_t)blockIdx.x * L_;
  ushort4 v = *(const ushort4*)&ob[base + t*4];
  float r[4] = {bf2f(v.x), bf2f(v.y), bf2f(v.z), bf2f(v.w)};
#pragma unroll
  for (int j = 0; j < 4; ++j) {
    float u = (r[j] - mean) * inv * w + bb;
    float m;
    if (u > 15.f) m = u;
    else {
      float e = expf(u);
      float a = 1.f + e;
      float a2 = a*a;
      m = u * (a2 - 1.f) / (a2 + 1.f);
    }
    r[j] = m;
  }
  *(float4*)&o[base + t*4] = make_float4(r[0], r[1], r[2], r[3]);
}

extern "C" void kernel_launch(void* const* d_in, const int* in_sizes, int n_in,
                              void* d_out, int out_size, void* d_ws, size_t ws_size,
                              hipStream_t stream) {
  const float* x       = (const float*)d_in[0];
  const float* W_in    = (const float*)d_in[1];
  const float* conv_w  = (const float*)d_in[2];
  const float* conv_b  = (const float*)d_in[3];
  const float* dt_bias = (const float*)d_in[4];
  const float* A_log   = (const float*)d_in[5];
  const float* Dp      = (const float*)d_in[6];
  const float* rms_w   = (const float*)d_in[7];
  const float* W_out   = (const float*)d_in[8];
  const float* gn_w    = (const float*)d_in[9];
  const float* gn_b    = (const float*)d_in[10];
  float* out = (float*)d_out;
  float* ws  = (float*)d_ws;

  ushort* zxb   = (ushort*)(ws + OFF_ZX);
  ushort* xcb   = (ushort*)(ws + OFF_XC);
  float*  dtb   = ws + OFF_DT;
  float*  acs   = ws + OFF_ACS;
  ushort* S0b   = (ushort*)(ws + OFF_S0);
  float*  st    = ws + OFF_ST;
  float*  pv    = ws + OFF_PV;
  ushort* Ybb   = (ushort*)(ws + OFF_Y);
  ushort* ynbf  = (ushort*)(ws + OFF_YNB);
  ushort* xbf   = (ushort*)(ws + OFF_XBF);
  ushort* wbf   = (ushort*)(ws + OFF_WBF);
  ushort* wobf  = (ushort*)(ws + OFF_WOBF);
  float2* gnp   = (float2*)(ws + OFF_GNP);
  ushort* btg   = (ushort*)(ws + OFF_BT);
  ushort* outb  = (ushort*)(ws + OFF_OUTB);

  k_prep         <<<dim3(512+1296+512+1), 256, 0, stream>>>(x, W_in, W_out, xbf, wbf, wobf, gnp);
  k_gemm_in_mfma <<<dim3(NZX/64, M_/128), 256, 0, stream>>>(xbf, wbf, zxb);
  k_dt_direct    <<<dim3(M_/16), 256, 0, stream>>>(x, W_in, dt_bias, dtb);
  k_conv         <<<dim3(3, M_/8), 256, 0, stream>>>(zxb, conv_w, conv_b, xcb, btg);
  k_s0_mfma      <<<dim3(4, 4, B_*NC), 256, 0, stream>>>(xcb, S0b);
  k_states_mfma  <<<dim3(B_*NC, NH), 256, 0, stream>>>(xcb, btg, dtb, A_log, acs, st);
  k_scan         <<<dim3(B_, NH), 256, 0, stream>>>(acs, st, pv);
  k_y_mfma       <<<dim3(B_*NC, NH), 256, 0, stream>>>(xcb, dtb, acs, S0b, pv, Dp, Ybb);
  k_rms          <<<dim3(M_), 256, 0, stream>>>(zxb, Ybb, rms_w, ynbf);
  k_gemm_out_mfma<<<dim3(DM/64, M_/128), 256, 0, stream>>>(ynbf, wobf, outb, gnp);
  k_gn_apply     <<<dim3(B_*DM), 256, 0, stream>>>(gnp, gn_w, gn_b, outb, out);
}